// Round 3
// baseline (1271.867 us; speedup 1.0000x reference)
//
#include <hip/hip_runtime.h>
#include <cstdio>

typedef long long ll;
typedef __bf16 bf16x8 __attribute__((ext_vector_type(8)));
typedef float f32x4 __attribute__((ext_vector_type(4)));

#define BB 4
#define NN 4096
#define CC 256
#define HH 512
#define GNUM 4
#define GS1 128
#define KNN 10

#define SC1 0.08838834764831845f   // 1/sqrt(128)
#define SC2 0.044194173824159216f  // 1/sqrt(512)

__device__ inline unsigned pk2(float x, float y) {
  unsigned a = __float_as_uint(x), b = __float_as_uint(y);
  a = (a + 0x7FFFu + ((a >> 16) & 1u)) >> 16;
  b = (b + 0x7FFFu + ((b >> 16) & 1u)) >> 16;
  return a | (b << 16);
}
__device__ inline unsigned short bf1(float x) {
  unsigned a = __float_as_uint(x);
  return (unsigned short)((a + 0x7FFFu + ((a >> 16) & 1u)) >> 16);
}
__device__ inline int sw16(int r) { return ((r ^ (r >> 3)) & 7) << 4; }

// ---------------- bf16 MFMA GEMM: C[m][n] = A[m][k] * B[k][n] ----------------
template<bool ATRANS, int EPI>
__global__ __launch_bounds__(256, 2) void mgemm_k(
    const float* __restrict__ A, const float* __restrict__ Bw,
    const float* __restrict__ bias, float* __restrict__ Cout,
    const float* __restrict__ pre,
    int M, int N, int K, int lda, ll strideA, ll strideC)
{
  const int z = blockIdx.z;
  A += (ll)z * strideA;
  const int bm = blockIdx.y * 128;
  const int bn = blockIdx.x * 128;
  __shared__ alignas(16) char smem[32768];
  char* smA = smem;
  char* smB = smem + 16384;
  const int tid = threadIdx.x;
  const int lane = tid & 63, w = tid >> 6;
  const int lr = lane & 15, lg = lane >> 4;
  const int wm = (w & 1) * 64, wn = (w >> 1) * 64;

  f32x4 acc[4][4] = {};

  for (int k0 = 0; k0 < K; k0 += 64) {
    if (!ATRANS) {
      #pragma unroll
      for (int p = 0; p < 8; ++p) {
        const int r = p * 16 + (tid >> 4);
        const int c = (tid & 15) * 4;
        const float4 v = *reinterpret_cast<const float4*>(A + (ll)(bm + r) * lda + (k0 + c));
        *reinterpret_cast<uint2*>(smA + r * 128 + ((c * 2) ^ sw16(r))) =
            make_uint2(pk2(v.x, v.y), pk2(v.z, v.w));
      }
    } else {
      #pragma unroll
      for (int p = 0; p < 2; ++p) {
        const int bb = p * 256 + tid;
        const int mb = (bb & 31) * 4, kb = (bb >> 5) * 4;
        const float4 l0 = *reinterpret_cast<const float4*>(A + (ll)(k0 + kb + 0) * lda + (bm + mb));
        const float4 l1 = *reinterpret_cast<const float4*>(A + (ll)(k0 + kb + 1) * lda + (bm + mb));
        const float4 l2 = *reinterpret_cast<const float4*>(A + (ll)(k0 + kb + 2) * lda + (bm + mb));
        const float4 l3 = *reinterpret_cast<const float4*>(A + (ll)(k0 + kb + 3) * lda + (bm + mb));
        *reinterpret_cast<uint2*>(smA + (mb + 0) * 128 + ((kb * 2) ^ sw16(mb + 0))) = make_uint2(pk2(l0.x, l1.x), pk2(l2.x, l3.x));
        *reinterpret_cast<uint2*>(smA + (mb + 1) * 128 + ((kb * 2) ^ sw16(mb + 1))) = make_uint2(pk2(l0.y, l1.y), pk2(l2.y, l3.y));
        *reinterpret_cast<uint2*>(smA + (mb + 2) * 128 + ((kb * 2) ^ sw16(mb + 2))) = make_uint2(pk2(l0.z, l1.z), pk2(l2.z, l3.z));
        *reinterpret_cast<uint2*>(smA + (mb + 3) * 128 + ((kb * 2) ^ sw16(mb + 3))) = make_uint2(pk2(l0.w, l1.w), pk2(l2.w, l3.w));
      }
    }
    #pragma unroll
    for (int p = 0; p < 2; ++p) {
      const int bb = p * 256 + tid;
      const int nb = (bb & 31) * 4, kb = (bb >> 5) * 4;
      const float4 l0 = *reinterpret_cast<const float4*>(Bw + (ll)(k0 + kb + 0) * N + (bn + nb));
      const float4 l1 = *reinterpret_cast<const float4*>(Bw + (ll)(k0 + kb + 1) * N + (bn + nb));
      const float4 l2 = *reinterpret_cast<const float4*>(Bw + (ll)(k0 + kb + 2) * N + (bn + nb));
      const float4 l3 = *reinterpret_cast<const float4*>(Bw + (ll)(k0 + kb + 3) * N + (bn + nb));
      *reinterpret_cast<uint2*>(smB + (nb + 0) * 128 + ((kb * 2) ^ sw16(nb + 0))) = make_uint2(pk2(l0.x, l1.x), pk2(l2.x, l3.x));
      *reinterpret_cast<uint2*>(smB + (nb + 1) * 128 + ((kb * 2) ^ sw16(nb + 1))) = make_uint2(pk2(l0.y, l1.y), pk2(l2.y, l3.y));
      *reinterpret_cast<uint2*>(smB + (nb + 2) * 128 + ((kb * 2) ^ sw16(nb + 2))) = make_uint2(pk2(l0.z, l1.z), pk2(l2.z, l3.z));
      *reinterpret_cast<uint2*>(smB + (nb + 3) * 128 + ((kb * 2) ^ sw16(nb + 3))) = make_uint2(pk2(l0.w, l1.w), pk2(l2.w, l3.w));
    }
    __syncthreads();

    #pragma unroll
    for (int ks = 0; ks < 2; ++ks) {
      bf16x8 af[4], bfr[4];
      #pragma unroll
      for (int mi = 0; mi < 4; ++mi) {
        const int r = wm + mi * 16 + lr;
        af[mi] = *reinterpret_cast<const bf16x8*>(smA + r * 128 + ((((ks << 2) + lg) << 4) ^ sw16(r)));
      }
      #pragma unroll
      for (int ni = 0; ni < 4; ++ni) {
        const int r = wn + ni * 16 + lr;
        bfr[ni] = *reinterpret_cast<const bf16x8*>(smB + r * 128 + ((((ks << 2) + lg) << 4) ^ sw16(r)));
      }
      #pragma unroll
      for (int mi = 0; mi < 4; ++mi)
        #pragma unroll
        for (int ni = 0; ni < 4; ++ni)
          acc[mi][ni] = __builtin_amdgcn_mfma_f32_16x16x32_bf16(af[mi], bfr[ni], acc[mi][ni], 0, 0, 0);
    }
    __syncthreads();
  }

  const ll cb = (ll)z * strideC;
  #pragma unroll
  for (int ni = 0; ni < 4; ++ni) {
    const int col = bn + wn + ni * 16 + lr;
    const float bv = (EPI != 0) ? bias[col] : 0.f;
    #pragma unroll
    for (int mi = 0; mi < 4; ++mi) {
      const int row0 = bm + wm + mi * 16 + lg * 4;
      if (EPI == 4) {
        const size_t o = ((size_t)z * N + col) * (size_t)M + row0;
        const float4 pv = *reinterpret_cast<const float4*>(pre + o);
        float4 r;
        r.x = acc[mi][ni][0] + bv + pv.x;
        r.y = acc[mi][ni][1] + bv + pv.y;
        r.z = acc[mi][ni][2] + bv + pv.z;
        r.w = acc[mi][ni][3] + bv + pv.w;
        *reinterpret_cast<float4*>(Cout + o) = r;
      } else {
        #pragma unroll
        for (int i = 0; i < 4; ++i) {
          float val = acc[mi][ni][i] + bv;
          if (EPI == 2) val = fmaxf(val, 0.f);
          if (EPI == 3) Cout[cb + (ll)(row0 + i) * N + col] += val;
          else          Cout[cb + (ll)(row0 + i) * N + col] = val;
        }
      }
    }
  }
}

// ---------------- fused branch-1 chain: P = (relu((X@WD2)@fgh1+b1))@fgh2+b2 ----------------
__device__ __forceinline__ void gemm128(const char* smA, const char* smW, int wrow, int lr, int lg,
                                        f32x4 acc[8]) {
  #pragma unroll
  for (int ks = 0; ks < 4; ++ks) {
    const int koff = (ks * 4 + lg) * 16;
    const int ra = wrow + lr;
    const bf16x8 a = *reinterpret_cast<const bf16x8*>(smA + ra * 256 + (koff ^ sw16(ra)));
    #pragma unroll
    for (int ni = 0; ni < 8; ++ni) {
      const int rn = ni * 16 + lr;
      const bf16x8 b = *reinterpret_cast<const bf16x8*>(smW + rn * 256 + (koff ^ sw16(rn)));
      acc[ni] = __builtin_amdgcn_mfma_f32_16x16x32_bf16(a, b, acc[ni], 0, 0, 0);
    }
  }
}

__device__ __forceinline__ void stageWT(const float* __restrict__ W, char* smW, int tid) {
  #pragma unroll
  for (int p = 0; p < 2; ++p) {
    const int bb = p * 512 + tid;
    const int nb = (bb & 31) * 4, kb = (bb >> 5) * 4;
    const float4 l0 = *reinterpret_cast<const float4*>(W + (kb + 0) * 128 + nb);
    const float4 l1 = *reinterpret_cast<const float4*>(W + (kb + 1) * 128 + nb);
    const float4 l2 = *reinterpret_cast<const float4*>(W + (kb + 2) * 128 + nb);
    const float4 l3 = *reinterpret_cast<const float4*>(W + (kb + 3) * 128 + nb);
    *reinterpret_cast<uint2*>(smW + (nb + 0) * 256 + ((kb * 2) ^ sw16(nb + 0))) = make_uint2(pk2(l0.x, l1.x), pk2(l2.x, l3.x));
    *reinterpret_cast<uint2*>(smW + (nb + 1) * 256 + ((kb * 2) ^ sw16(nb + 1))) = make_uint2(pk2(l0.y, l1.y), pk2(l2.y, l3.y));
    *reinterpret_cast<uint2*>(smW + (nb + 2) * 256 + ((kb * 2) ^ sw16(nb + 2))) = make_uint2(pk2(l0.z, l1.z), pk2(l2.z, l3.z));
    *reinterpret_cast<uint2*>(smW + (nb + 3) * 256 + ((kb * 2) ^ sw16(nb + 3))) = make_uint2(pk2(l0.w, l1.w), pk2(l2.w, l3.w));
  }
}

__global__ __launch_bounds__(512, 4) void fused1_k(
    const float* __restrict__ X,
    const float* __restrict__ wqs2, const float* __restrict__ wks2,
    const float* __restrict__ w2g, const float* __restrict__ b2g,
    const float* __restrict__ w3g, const float* __restrict__ b3g,
    float* __restrict__ P)
{
  __shared__ alignas(16) char smT[32768];
  __shared__ alignas(16) char smW[32768];
  const int tid = threadIdx.x;
  const int lane = tid & 63, w = tid >> 6;
  const int lr = lane & 15, lg = lane >> 4;
  const int wrow = w * 16;
  const ll blockRow = (ll)blockIdx.x * 128;
  const float* Xb = X + blockRow * 128;

  float b2r[8], b3r[8];
  #pragma unroll
  for (int ni = 0; ni < 8; ++ni) { b2r[ni] = b2g[ni * 16 + lr]; b3r[ni] = b3g[ni * 16 + lr]; }

  // stage X tile [128r][128k] bf16 swizzled
  #pragma unroll
  for (int p = 0; p < 8; ++p) {
    const int i = p * 512 + tid;
    const int r = i >> 5, c4 = (i & 31) * 4;
    const float4 v = *reinterpret_cast<const float4*>(Xb + (ll)r * 128 + c4);
    *reinterpret_cast<uint2*>(smT + r * 256 + ((c4 * 2) ^ sw16(r))) =
        make_uint2(pk2(v.x, v.y), pk2(v.z, v.w));
  }
  // stage W1 = (wqs2 - wks2)^T -> [n][k]
  #pragma unroll
  for (int p = 0; p < 2; ++p) {
    const int bb = p * 512 + tid;
    const int nb = (bb & 31) * 4, kb = (bb >> 5) * 4;
    float4 l0 = *reinterpret_cast<const float4*>(wqs2 + (kb + 0) * 128 + nb);
    float4 l1 = *reinterpret_cast<const float4*>(wqs2 + (kb + 1) * 128 + nb);
    float4 l2 = *reinterpret_cast<const float4*>(wqs2 + (kb + 2) * 128 + nb);
    float4 l3 = *reinterpret_cast<const float4*>(wqs2 + (kb + 3) * 128 + nb);
    const float4 m0 = *reinterpret_cast<const float4*>(wks2 + (kb + 0) * 128 + nb);
    const float4 m1 = *reinterpret_cast<const float4*>(wks2 + (kb + 1) * 128 + nb);
    const float4 m2 = *reinterpret_cast<const float4*>(wks2 + (kb + 2) * 128 + nb);
    const float4 m3 = *reinterpret_cast<const float4*>(wks2 + (kb + 3) * 128 + nb);
    l0.x -= m0.x; l0.y -= m0.y; l0.z -= m0.z; l0.w -= m0.w;
    l1.x -= m1.x; l1.y -= m1.y; l1.z -= m1.z; l1.w -= m1.w;
    l2.x -= m2.x; l2.y -= m2.y; l2.z -= m2.z; l2.w -= m2.w;
    l3.x -= m3.x; l3.y -= m3.y; l3.z -= m3.z; l3.w -= m3.w;
    *reinterpret_cast<uint2*>(smW + (nb + 0) * 256 + ((kb * 2) ^ sw16(nb + 0))) = make_uint2(pk2(l0.x, l1.x), pk2(l2.x, l3.x));
    *reinterpret_cast<uint2*>(smW + (nb + 1) * 256 + ((kb * 2) ^ sw16(nb + 1))) = make_uint2(pk2(l0.y, l1.y), pk2(l2.y, l3.y));
    *reinterpret_cast<uint2*>(smW + (nb + 2) * 256 + ((kb * 2) ^ sw16(nb + 2))) = make_uint2(pk2(l0.z, l1.z), pk2(l2.z, l3.z));
    *reinterpret_cast<uint2*>(smW + (nb + 3) * 256 + ((kb * 2) ^ sw16(nb + 3))) = make_uint2(pk2(l0.w, l1.w), pk2(l2.w, l3.w));
  }
  __syncthreads();

  f32x4 acc[8];
  #pragma unroll
  for (int ni = 0; ni < 8; ++ni) acc[ni] = f32x4{0.f, 0.f, 0.f, 0.f};
  gemm128(smT, smW, wrow, lr, lg, acc);        // T1 = X @ WD2
  __syncthreads();

  // write T1 -> smT (bf16), stage W2 (fgh1)
  #pragma unroll
  for (int ni = 0; ni < 8; ++ni)
    #pragma unroll
    for (int i = 0; i < 4; ++i) {
      const int r = wrow + lg * 4 + i;
      *reinterpret_cast<unsigned short*>(smT + r * 256 + (((ni * 16 + lr) * 2) ^ sw16(r))) = bf1(acc[ni][i]);
    }
  stageWT(w2g, smW, tid);
  __syncthreads();

  #pragma unroll
  for (int ni = 0; ni < 8; ++ni) acc[ni] = f32x4{0.f, 0.f, 0.f, 0.f};
  gemm128(smT, smW, wrow, lr, lg, acc);        // U = T1 @ fgh1
  __syncthreads();

  // write relu(U + b1) -> smT, stage W3 (fgh2)
  #pragma unroll
  for (int ni = 0; ni < 8; ++ni)
    #pragma unroll
    for (int i = 0; i < 4; ++i) {
      const int r = wrow + lg * 4 + i;
      *reinterpret_cast<unsigned short*>(smT + r * 256 + (((ni * 16 + lr) * 2) ^ sw16(r))) =
          bf1(fmaxf(acc[ni][i] + b2r[ni], 0.f));
    }
  stageWT(w3g, smW, tid);
  __syncthreads();

  #pragma unroll
  for (int ni = 0; ni < 8; ++ni) acc[ni] = f32x4{0.f, 0.f, 0.f, 0.f};
  gemm128(smT, smW, wrow, lr, lg, acc);        // P = U @ fgh2

  #pragma unroll
  for (int ni = 0; ni < 8; ++ni)
    #pragma unroll
    for (int i = 0; i < 4; ++i) {
      const ll r = blockRow + wrow + lg * 4 + i;
      P[r * 128 + ni * 16 + lr] = acc[ni][i] + b3r[ni];
    }
}

// ---------------- online softmax partial reduce ----------------
__device__ inline void omax_upd(float& m, float& s, float v, float scale) {
  if (v > m) { s = s * expf((m - v) * scale) + 1.0f; m = v; }
  else       { s += expf((v - m) * scale); }
}
__device__ inline void omax_merge(float& m, float& s, float m2, float s2, float scale) {
  if (m2 > m) { s = s * expf((m - m2) * scale) + s2; m = m2; }
  else        { s += s2 * expf((m2 - m) * scale); }
}

__global__ __launch_bounds__(256) void red1_k(const float* __restrict__ P,
                                              float* __restrict__ PM, float* __restrict__ PS) {
  const int bid = blockIdx.x;
  const int b = bid >> 7, g = (bid >> 5) & 3, seg = bid & 31;
  const int d = threadIdx.x & 127, half = threadIdx.x >> 7;
  const size_t base = (size_t)b * NN * HH + g * GS1 + d;
  float m = -3.4e38f, s = 0.f;
  const int n0 = seg * 128 + half * 64;
  for (int n = n0; n < n0 + 64; ++n)
    omax_upd(m, s, P[base + (size_t)n * HH], SC1);
  __shared__ float sm[256], ss[256];
  sm[threadIdx.x] = m; ss[threadIdx.x] = s;
  __syncthreads();
  if (half == 0) {
    omax_merge(m, s, sm[threadIdx.x + 128], ss[threadIdx.x + 128], SC1);
    const int c = b * HH + g * GS1 + d;
    PM[(size_t)seg * 2048 + c] = m;
    PS[(size_t)seg * 2048 + c] = s;
  }
}

__global__ __launch_bounds__(256) void red2_k(const float* __restrict__ A2,
                                              float* __restrict__ PM, float* __restrict__ PS) {
  const int bid = blockIdx.x;
  const int b = bid >> 5, hb = (bid >> 3) & 3, seg = bid & 7;
  const int hl = threadIdx.x & 127, half = threadIdx.x >> 7;
  const int h = hb * 128 + hl;
  const size_t base = (size_t)b * 1024 * HH + h;
  float m = -3.4e38f, s = 0.f;
  const int r0 = seg * 128 + half * 64;
  for (int r = r0; r < r0 + 64; ++r)
    omax_upd(m, s, A2[base + (size_t)r * HH], SC2);
  __shared__ float sm[256], ss[256];
  sm[threadIdx.x] = m; ss[threadIdx.x] = s;
  __syncthreads();
  if (half == 0) {
    omax_merge(m, s, sm[threadIdx.x + 128], ss[threadIdx.x + 128], SC2);
    const int c = b * HH + h;
    PM[(size_t)seg * 2048 + c] = m;
    PS[(size_t)seg * 2048 + c] = s;
  }
}

__global__ __launch_bounds__(256) void combineN_k(const float* __restrict__ PM, const float* __restrict__ PS,
                                                  float* __restrict__ Mo, float* __restrict__ Ro,
                                                  int nseg, float scale) {
  const int c = blockIdx.x * 256 + threadIdx.x;
  float m = -3.4e38f, s = 0.f;
  for (int seg = 0; seg < nseg; ++seg)
    omax_merge(m, s, PM[(size_t)seg * 2048 + c], PS[(size_t)seg * 2048 + c], scale);
  Mo[c] = m;
  Ro[c] = 1.0f / s;
}

// ---------------- KNN: 8 lanes/query, register top-10, bitonic shuffle merge ----------------
__device__ __forceinline__ void ce10(float& d0, int& i0, float& d1, int& i1) {
  const bool sw = (d1 < d0) || (d1 == d0 && i1 < i0);
  const float td = sw ? d1 : d0, tD = sw ? d0 : d1;
  const int ti = sw ? i1 : i0, tI = sw ? i0 : i1;
  d0 = td; i0 = ti; d1 = tD; i1 = tI;
}

__global__ __launch_bounds__(256) void knn2_k(const float* __restrict__ xyz, int* __restrict__ idx) {
  const int tid = threadIdx.x;
  const int g = tid & 7, ql = tid >> 3;
  const int q = blockIdx.x * 32 + ql;
  const int b = q >> 12, n = q & (NN - 1);
  const float* xb = xyz + (size_t)b * NN * 3;
  const float qx = xb[n * 3], qy = xb[n * 3 + 1], qz = xb[n * 3 + 2];
  const float qn = fmaf(qz, qz, fmaf(qy, qy, qx * qx));

  __shared__ float4 pts[512];
  float bd[KNN]; int bi[KNN];
  #pragma unroll
  for (int k = 0; k < KNN; ++k) { bd[k] = 3.4e38f; bi[k] = 0x7fffffff; }

  for (int t0 = 0; t0 < NN; t0 += 512) {
    __syncthreads();
    #pragma unroll
    for (int p0 = 0; p0 < 2; ++p0) {
      const int p = p0 * 256 + tid;
      const int m = t0 + p;
      const float px = xb[m * 3], py = xb[m * 3 + 1], pz = xb[m * 3 + 2];
      pts[p] = make_float4(px, py, pz, fmaf(pz, pz, fmaf(py, py, px * px)));
    }
    __syncthreads();
    const int base = g * 64;
    #pragma unroll 4
    for (int i2 = 0; i2 < 64; ++i2) {
      const int p = base + ((i2 + g) & 63);
      const float4 pt = pts[p];
      const float dot = fmaf(qz, pt.z, fmaf(qy, pt.y, qx * pt.x));
      const float dist = fmaf(-2.f, dot, qn + pt.w);
      if (dist < bd[KNN - 1]) {
        const int m = t0 + p;
        bd[KNN - 1] = dist; bi[KNN - 1] = m;
        #pragma unroll
        for (int k = KNN - 1; k >= 1; --k) {
          const bool sw = (bd[k] < bd[k - 1]) || (bd[k] == bd[k - 1] && bi[k] < bi[k - 1]);
          const float td = sw ? bd[k] : bd[k - 1];
          const float tD = sw ? bd[k - 1] : bd[k];
          const int ti = sw ? bi[k] : bi[k - 1];
          const int tI = sw ? bi[k - 1] : bi[k];
          bd[k - 1] = td; bi[k - 1] = ti; bd[k] = tD; bi[k] = tI;
        }
      }
    }
  }

  // merge 8 sorted lists via bitonic shuffle rounds (pad to 16)
  float ad[16]; int ai[16];
  #pragma unroll
  for (int k = 0; k < KNN; ++k) { ad[k] = bd[k]; ai[k] = bi[k]; }
  #pragma unroll
  for (int k = KNN; k < 16; ++k) { ad[k] = 3.4e38f; ai[k] = 0x7fffffff; }

  #pragma unroll
  for (int s = 1; s < 8; s <<= 1) {
    float pd[16]; int pi[16];
    #pragma unroll
    for (int k = 0; k < 16; ++k) { pd[k] = __shfl_xor(ad[k], s); pi[k] = __shfl_xor(ai[k], s); }
    #pragma unroll
    for (int k = 0; k < 16; ++k) {
      const float od = pd[15 - k]; const int oi = pi[15 - k];
      const bool take = (od < ad[k]) || (od == ad[k] && oi < ai[k]);
      ad[k] = take ? od : ad[k];
      ai[k] = take ? oi : ai[k];
    }
    #pragma unroll
    for (int st = 8; st >= 1; st >>= 1)
      #pragma unroll
      for (int k = 0; k < 16; ++k)
        if ((k & st) == 0) ce10(ad[k], ai[k], ad[k + st], ai[k + st]);
  }

  if (g == 0) {
    #pragma unroll
    for (int k = 0; k < KNN; ++k) idx[(size_t)q * KNN + k] = ai[k];
  }
}

// ---------------- pos-enc hidden mean ----------------
__global__ __launch_bounds__(256) void posenc_k(const float* __restrict__ xyz, const int* __restrict__ idx,
                                                const float* __restrict__ fd1w, const float* __restrict__ fd1b,
                                                float* __restrict__ hmean) {
  const int bn = blockIdx.x;
  const int b = bn >> 12, n = bn & (NN - 1);
  const float* xb = xyz + (size_t)b * NN * 3;
  const float qx = xb[n * 3], qy = xb[n * 3 + 1], qz = xb[n * 3 + 2];
  __shared__ float dxyz[KNN][3];
  if (threadIdx.x < KNN) {
    const int m = idx[(size_t)bn * KNN + threadIdx.x];
    dxyz[threadIdx.x][0] = qx - xb[m * 3];
    dxyz[threadIdx.x][1] = qy - xb[m * 3 + 1];
    dxyz[threadIdx.x][2] = qz - xb[m * 3 + 2];
  }
  __syncthreads();
  for (int h = threadIdx.x; h < HH; h += 256) {
    const float w0 = fd1w[h], w1 = fd1w[HH + h], w2 = fd1w[2 * HH + h], bb = fd1b[h];
    float acc = 0.f;
    #pragma unroll
    for (int k = 0; k < KNN; ++k)
      acc += fmaxf(fmaf(dxyz[k][2], w2, fmaf(dxyz[k][1], w1, dxyz[k][0] * w0)) + bb, 0.f);
    hmean[(size_t)bn * HH + h] = acc * 0.1f;
  }
}

// ---------------- res = (softmax1(P) + softmax2(A2)) * (v + posenc) ----------------
__global__ __launch_bounds__(256) void res_k(const float* __restrict__ P, const float* __restrict__ A2,
                                             const float* __restrict__ V,
                                             const float* __restrict__ M1, const float* __restrict__ R1,
                                             const float* __restrict__ M2, const float* __restrict__ R2,
                                             float* __restrict__ R) {
  const size_t i4 = (size_t)blockIdx.x * 256 + threadIdx.x;
  const size_t i = i4 * 4;
  const int b = (int)(i >> 21);
  const int n = (int)((i >> 9) & (NN - 1));
  const int h = (int)(i & (HH - 1));
  const int c = (b << 9) + h;
  const size_t j = (((size_t)b * 1024 + (n & 1023)) << 9) + h;
  const float4 p = *reinterpret_cast<const float4*>(P + i);
  const float4 a = *reinterpret_cast<const float4*>(A2 + j);
  const float4 v = *reinterpret_cast<const float4*>(V + i);
  const float4 m1 = *reinterpret_cast<const float4*>(M1 + c);
  const float4 r1 = *reinterpret_cast<const float4*>(R1 + c);
  const float4 m2 = *reinterpret_cast<const float4*>(M2 + c);
  const float4 r2 = *reinterpret_cast<const float4*>(R2 + c);
  float4 r;
  r.x = (expf((p.x - m1.x) * SC1) * r1.x + expf((a.x - m2.x) * SC2) * r2.x) * v.x;
  r.y = (expf((p.y - m1.y) * SC1) * r1.y + expf((a.y - m2.y) * SC2) * r2.y) * v.y;
  r.z = (expf((p.z - m1.z) * SC1) * r1.z + expf((a.z - m2.z) * SC2) * r2.z) * v.z;
  r.w = (expf((p.w - m1.w) * SC1) * r1.w + expf((a.w - m2.w) * SC2) * r2.w) * v.w;
  *reinterpret_cast<float4*>(R + i) = r;
}

__global__ void sub_k(const float* __restrict__ a, const float* __restrict__ b, float* __restrict__ o, int n) {
  const int i = blockIdx.x * 256 + threadIdx.x;
  if (i < n) o[i] = a[i] - b[i];
}

__global__ void copy_k(const float* __restrict__ a, float* __restrict__ o, int n) {
  const int i = blockIdx.x * 256 + threadIdx.x;
  if (i < n) o[i] = a[i];
}

extern "C" void kernel_launch(void* const* d_in, const int* in_sizes, int n_in,
                              void* d_out, int out_size, void* d_ws, size_t ws_size,
                              hipStream_t stream) {
  const float* features = (const float*)d_in[0];
  const float* xyz      = (const float*)d_in[1];
  const float* fc1_w    = (const float*)d_in[2];
  const float* fc1_b    = (const float*)d_in[3];
  const float* fc2_w    = (const float*)d_in[4];
  const float* fc2_b    = (const float*)d_in[5];
  const float* fd1_w    = (const float*)d_in[6];
  const float* fd1_b    = (const float*)d_in[7];
  const float* fd2_w    = (const float*)d_in[8];
  const float* fd2_b    = (const float*)d_in[9];
  const float* fg1_w    = (const float*)d_in[10];
  const float* fg1_b    = (const float*)d_in[11];
  const float* fg2_w    = (const float*)d_in[12];
  const float* fg2_b    = (const float*)d_in[13];
  const float* fgh1_w   = (const float*)d_in[14];
  const float* fgh1_b   = (const float*)d_in[15];
  const float* fgh2_w   = (const float*)d_in[16];
  const float* fgh2_b   = (const float*)d_in[17];
  const float* wqs      = (const float*)d_in[18];
  const float* wks      = (const float*)d_in[19];
  const float* wvs      = (const float*)d_in[20];
  const float* wqs2     = (const float*)d_in[21];
  const float* wks2     = (const float*)d_in[22];
  float* out = (float*)d_out;

  const size_t BNH = (size_t)BB * NN * HH;
  float* X   = (float*)d_ws;
  float* P   = X + BNH;
  float* Q   = P + BNH;
  float* V   = Q + BNH;
  float* S1  = V + BNH;
  float* S2  = S1 + (size_t)BB * 1024 * HH;
  float* WD  = S2 + (size_t)BB * 1024 * HH;
  int*   IDX = (int*)(WD + HH * HH);
  float* PM1 = (float*)(IDX + (size_t)BB * NN * KNN);
  float* PS1 = PM1 + 32 * 2048;
  float* PM2 = PS1 + 32 * 2048;
  float* PS2 = PM2 + 8 * 2048;
  float* M1  = PS2 + 8 * 2048;
  float* R1  = M1 + 2048;
  float* M2  = R1 + 2048;
  float* R2  = M2 + 2048;
  const size_t need = ((char*)(R2 + 2048)) - (char*)d_ws;
  if (ws_size < need) {
    fprintf(stderr, "kernel_launch: ws too small: %zu < %zu\n", ws_size, need);
    return;
  }

  sub_k<<<(HH * HH + 255) / 256, 256, 0, stream>>>(wqs, wks, WD, HH * HH);

  // x = features^T @ fc1_w + fc1_b
  mgemm_k<true, 1><<<dim3(HH / 128, NN / 128, BB), 256, 0, stream>>>(
      features, fc1_w, fc1_b, X, nullptr, NN, HH, CC, NN, (ll)CC * NN, (ll)NN * HH);

  // branch 1 fused chain -> P
  fused1_k<<<512, 512, 0, stream>>>(X, wqs2, wks2, fgh1_w, fgh1_b, fgh2_w, fgh2_b, P);
  red1_k<<<512, 256, 0, stream>>>(P, PM1, PS1);
  combineN_k<<<8, 256, 0, stream>>>(PM1, PS1, M1, R1, 32, SC1);

  // branch 2
  mgemm_k<false, 0><<<dim3(HH / 128, 1024 / 128, BB), 256, 0, stream>>>(
      X + (size_t)3072 * HH, WD, nullptr, S1, nullptr, 1024, HH, HH, HH, (ll)NN * HH, (ll)1024 * HH);
  mgemm_k<false, 2><<<dim3(HH / 128, BB * 1024 / 128, 1), 256, 0, stream>>>(
      S1, fg1_w, fg1_b, S2, nullptr, BB * 1024, HH, HH, HH, 0, 0);
  mgemm_k<false, 1><<<dim3(HH / 128, BB * 1024 / 128, 1), 256, 0, stream>>>(
      S2, fg2_w, fg2_b, S1, nullptr, BB * 1024, HH, HH, HH, 0, 0);
  red2_k<<<128, 256, 0, stream>>>(S1, PM2, PS2);
  combineN_k<<<8, 256, 0, stream>>>(PM2, PS2, M2, R2, 8, SC2);

  // v = x @ wvs
  mgemm_k<false, 0><<<dim3(HH / 128, BB * NN / 128, 1), 256, 0, stream>>>(
      X, wvs, nullptr, V, nullptr, BB * NN, HH, HH, HH, 0, 0);

  // knn + pos-enc
  knn2_k<<<BB * NN / 32, 256, 0, stream>>>(xyz, IDX);
  posenc_k<<<BB * NN, 256, 0, stream>>>(xyz, IDX, fd1_w, fd1_b, Q);
  mgemm_k<false, 3><<<dim3(HH / 128, BB * NN / 128, 1), 256, 0, stream>>>(
      Q, fd2_w, fd2_b, V, nullptr, BB * NN, HH, HH, HH, 0, 0);

  // res -> X
  res_k<<<(int)(BNH / 4 / 256), 256, 0, stream>>>(P, S1, V, M1, R1, M2, R2, X);

  // out = swap(res @ fc2_w + fc2_b) + features
  mgemm_k<false, 4><<<dim3(CC / 128, NN / 128, BB), 256, 0, stream>>>(
      X, fc2_w, fc2_b, out, features, NN, CC, HH, HH, (ll)NN * HH, 0);

  copy_k<<<(BB * NN * 3 + 255) / 256, 256, 0, stream>>>(xyz, out + (size_t)BB * CC * NN, BB * NN * 3);
}

// Round 4
// 576.755 us; speedup vs baseline: 2.2052x; 2.2052x over previous
//
#include <hip/hip_runtime.h>
#include <cstdio>

typedef long long ll;
typedef unsigned long long ull;
typedef __bf16 bf16x8 __attribute__((ext_vector_type(8)));
typedef float f32x4 __attribute__((ext_vector_type(4)));

#define BB 4
#define NN 4096
#define CC 256
#define HH 512
#define GNUM 4
#define GS1 128
#define KNN 10

#define SC1 0.08838834764831845f   // 1/sqrt(128)
#define SC2 0.044194173824159216f  // 1/sqrt(512)

__device__ inline unsigned pk2(float x, float y) {
  unsigned a = __float_as_uint(x), b = __float_as_uint(y);
  a = (a + 0x7FFFu + ((a >> 16) & 1u)) >> 16;
  b = (b + 0x7FFFu + ((b >> 16) & 1u)) >> 16;
  return a | (b << 16);
}
__device__ inline unsigned short bf1(float x) {
  unsigned a = __float_as_uint(x);
  return (unsigned short)((a + 0x7FFFu + ((a >> 16) & 1u)) >> 16);
}
__device__ inline int sw16(int r) { return ((r ^ (r >> 3)) & 7) << 4; }

// ---------------- bf16 MFMA GEMM: C[m][n] = A[m][k] * B[k][n] ----------------
template<bool ATRANS, int EPI>
__global__ __launch_bounds__(256, 2) void mgemm_k(
    const float* __restrict__ A, const float* __restrict__ Bw,
    const float* __restrict__ bias, float* __restrict__ Cout,
    const float* __restrict__ pre,
    int M, int N, int K, int lda, ll strideA, ll strideC)
{
  const int z = blockIdx.z;
  A += (ll)z * strideA;
  const int bm = blockIdx.y * 128;
  const int bn = blockIdx.x * 128;
  __shared__ alignas(16) char smem[32768];
  char* smA = smem;
  char* smB = smem + 16384;
  const int tid = threadIdx.x;
  const int lane = tid & 63, w = tid >> 6;
  const int lr = lane & 15, lg = lane >> 4;
  const int wm = (w & 1) * 64, wn = (w >> 1) * 64;

  f32x4 acc[4][4] = {};

  for (int k0 = 0; k0 < K; k0 += 64) {
    if (!ATRANS) {
      #pragma unroll
      for (int p = 0; p < 8; ++p) {
        const int r = p * 16 + (tid >> 4);
        const int c = (tid & 15) * 4;
        const float4 v = *reinterpret_cast<const float4*>(A + (ll)(bm + r) * lda + (k0 + c));
        *reinterpret_cast<uint2*>(smA + r * 128 + ((c * 2) ^ sw16(r))) =
            make_uint2(pk2(v.x, v.y), pk2(v.z, v.w));
      }
    } else {
      #pragma unroll
      for (int p = 0; p < 2; ++p) {
        const int bb = p * 256 + tid;
        const int mb = (bb & 31) * 4, kb = (bb >> 5) * 4;
        const float4 l0 = *reinterpret_cast<const float4*>(A + (ll)(k0 + kb + 0) * lda + (bm + mb));
        const float4 l1 = *reinterpret_cast<const float4*>(A + (ll)(k0 + kb + 1) * lda + (bm + mb));
        const float4 l2 = *reinterpret_cast<const float4*>(A + (ll)(k0 + kb + 2) * lda + (bm + mb));
        const float4 l3 = *reinterpret_cast<const float4*>(A + (ll)(k0 + kb + 3) * lda + (bm + mb));
        *reinterpret_cast<uint2*>(smA + (mb + 0) * 128 + ((kb * 2) ^ sw16(mb + 0))) = make_uint2(pk2(l0.x, l1.x), pk2(l2.x, l3.x));
        *reinterpret_cast<uint2*>(smA + (mb + 1) * 128 + ((kb * 2) ^ sw16(mb + 1))) = make_uint2(pk2(l0.y, l1.y), pk2(l2.y, l3.y));
        *reinterpret_cast<uint2*>(smA + (mb + 2) * 128 + ((kb * 2) ^ sw16(mb + 2))) = make_uint2(pk2(l0.z, l1.z), pk2(l2.z, l3.z));
        *reinterpret_cast<uint2*>(smA + (mb + 3) * 128 + ((kb * 2) ^ sw16(mb + 3))) = make_uint2(pk2(l0.w, l1.w), pk2(l2.w, l3.w));
      }
    }
    #pragma unroll
    for (int p = 0; p < 2; ++p) {
      const int bb = p * 256 + tid;
      const int nb = (bb & 31) * 4, kb = (bb >> 5) * 4;
      const float4 l0 = *reinterpret_cast<const float4*>(Bw + (ll)(k0 + kb + 0) * N + (bn + nb));
      const float4 l1 = *reinterpret_cast<const float4*>(Bw + (ll)(k0 + kb + 1) * N + (bn + nb));
      const float4 l2 = *reinterpret_cast<const float4*>(Bw + (ll)(k0 + kb + 2) * N + (bn + nb));
      const float4 l3 = *reinterpret_cast<const float4*>(Bw + (ll)(k0 + kb + 3) * N + (bn + nb));
      *reinterpret_cast<uint2*>(smB + (nb + 0) * 128 + ((kb * 2) ^ sw16(nb + 0))) = make_uint2(pk2(l0.x, l1.x), pk2(l2.x, l3.x));
      *reinterpret_cast<uint2*>(smB + (nb + 1) * 128 + ((kb * 2) ^ sw16(nb + 1))) = make_uint2(pk2(l0.y, l1.y), pk2(l2.y, l3.y));
      *reinterpret_cast<uint2*>(smB + (nb + 2) * 128 + ((kb * 2) ^ sw16(nb + 2))) = make_uint2(pk2(l0.z, l1.z), pk2(l2.z, l3.z));
      *reinterpret_cast<uint2*>(smB + (nb + 3) * 128 + ((kb * 2) ^ sw16(nb + 3))) = make_uint2(pk2(l0.w, l1.w), pk2(l2.w, l3.w));
    }
    __syncthreads();

    #pragma unroll
    for (int ks = 0; ks < 2; ++ks) {
      bf16x8 af[4], bfr[4];
      #pragma unroll
      for (int mi = 0; mi < 4; ++mi) {
        const int r = wm + mi * 16 + lr;
        af[mi] = *reinterpret_cast<const bf16x8*>(smA + r * 128 + ((((ks << 2) + lg) << 4) ^ sw16(r)));
      }
      #pragma unroll
      for (int ni = 0; ni < 4; ++ni) {
        const int r = wn + ni * 16 + lr;
        bfr[ni] = *reinterpret_cast<const bf16x8*>(smB + r * 128 + ((((ks << 2) + lg) << 4) ^ sw16(r)));
      }
      #pragma unroll
      for (int mi = 0; mi < 4; ++mi)
        #pragma unroll
        for (int ni = 0; ni < 4; ++ni)
          acc[mi][ni] = __builtin_amdgcn_mfma_f32_16x16x32_bf16(af[mi], bfr[ni], acc[mi][ni], 0, 0, 0);
    }
    __syncthreads();
  }

  const ll cb = (ll)z * strideC;
  #pragma unroll
  for (int ni = 0; ni < 4; ++ni) {
    const int col = bn + wn + ni * 16 + lr;
    const float bv = (EPI != 0) ? bias[col] : 0.f;
    #pragma unroll
    for (int mi = 0; mi < 4; ++mi) {
      const int row0 = bm + wm + mi * 16 + lg * 4;
      if (EPI == 4) {
        const size_t o = ((size_t)z * N + col) * (size_t)M + row0;
        const float4 pv = *reinterpret_cast<const float4*>(pre + o);
        float4 r;
        r.x = acc[mi][ni][0] + bv + pv.x;
        r.y = acc[mi][ni][1] + bv + pv.y;
        r.z = acc[mi][ni][2] + bv + pv.z;
        r.w = acc[mi][ni][3] + bv + pv.w;
        *reinterpret_cast<float4*>(Cout + o) = r;
      } else {
        #pragma unroll
        for (int i = 0; i < 4; ++i) {
          float val = acc[mi][ni][i] + bv;
          if (EPI == 2) val = fmaxf(val, 0.f);
          if (EPI == 3) Cout[cb + (ll)(row0 + i) * N + col] += val;
          else          Cout[cb + (ll)(row0 + i) * N + col] = val;
        }
      }
    }
  }
}

// ---------------- fused branch-1 chain: P = (relu((X@WD2)@fgh1+b1))@fgh2+b2 ----------------
__device__ __forceinline__ void gemm128(const char* smA, const char* smW, int wrow, int lr, int lg,
                                        f32x4 acc[8]) {
  #pragma unroll
  for (int ks = 0; ks < 4; ++ks) {
    const int koff = (ks * 4 + lg) * 16;
    const int ra = wrow + lr;
    const bf16x8 a = *reinterpret_cast<const bf16x8*>(smA + ra * 256 + (koff ^ sw16(ra)));
    #pragma unroll
    for (int ni = 0; ni < 8; ++ni) {
      const int rn = ni * 16 + lr;
      const bf16x8 b = *reinterpret_cast<const bf16x8*>(smW + rn * 256 + (koff ^ sw16(rn)));
      acc[ni] = __builtin_amdgcn_mfma_f32_16x16x32_bf16(a, b, acc[ni], 0, 0, 0);
    }
  }
}

__device__ __forceinline__ void stageWT(const float* __restrict__ W, char* smW, int tid) {
  #pragma unroll
  for (int p = 0; p < 2; ++p) {
    const int bb = p * 512 + tid;
    const int nb = (bb & 31) * 4, kb = (bb >> 5) * 4;
    const float4 l0 = *reinterpret_cast<const float4*>(W + (kb + 0) * 128 + nb);
    const float4 l1 = *reinterpret_cast<const float4*>(W + (kb + 1) * 128 + nb);
    const float4 l2 = *reinterpret_cast<const float4*>(W + (kb + 2) * 128 + nb);
    const float4 l3 = *reinterpret_cast<const float4*>(W + (kb + 3) * 128 + nb);
    *reinterpret_cast<uint2*>(smW + (nb + 0) * 256 + ((kb * 2) ^ sw16(nb + 0))) = make_uint2(pk2(l0.x, l1.x), pk2(l2.x, l3.x));
    *reinterpret_cast<uint2*>(smW + (nb + 1) * 256 + ((kb * 2) ^ sw16(nb + 1))) = make_uint2(pk2(l0.y, l1.y), pk2(l2.y, l3.y));
    *reinterpret_cast<uint2*>(smW + (nb + 2) * 256 + ((kb * 2) ^ sw16(nb + 2))) = make_uint2(pk2(l0.z, l1.z), pk2(l2.z, l3.z));
    *reinterpret_cast<uint2*>(smW + (nb + 3) * 256 + ((kb * 2) ^ sw16(nb + 3))) = make_uint2(pk2(l0.w, l1.w), pk2(l2.w, l3.w));
  }
}

__global__ __launch_bounds__(512, 4) void fused1_k(
    const float* __restrict__ X,
    const float* __restrict__ wqs2, const float* __restrict__ wks2,
    const float* __restrict__ w2g, const float* __restrict__ b2g,
    const float* __restrict__ w3g, const float* __restrict__ b3g,
    float* __restrict__ P)
{
  __shared__ alignas(16) char smT[32768];
  __shared__ alignas(16) char smW[32768];
  const int tid = threadIdx.x;
  const int lane = tid & 63, w = tid >> 6;
  const int lr = lane & 15, lg = lane >> 4;
  const int wrow = w * 16;
  const ll blockRow = (ll)blockIdx.x * 128;
  const float* Xb = X + blockRow * 128;

  float b2r[8], b3r[8];
  #pragma unroll
  for (int ni = 0; ni < 8; ++ni) { b2r[ni] = b2g[ni * 16 + lr]; b3r[ni] = b3g[ni * 16 + lr]; }

  #pragma unroll
  for (int p = 0; p < 8; ++p) {
    const int i = p * 512 + tid;
    const int r = i >> 5, c4 = (i & 31) * 4;
    const float4 v = *reinterpret_cast<const float4*>(Xb + (ll)r * 128 + c4);
    *reinterpret_cast<uint2*>(smT + r * 256 + ((c4 * 2) ^ sw16(r))) =
        make_uint2(pk2(v.x, v.y), pk2(v.z, v.w));
  }
  #pragma unroll
  for (int p = 0; p < 2; ++p) {
    const int bb = p * 512 + tid;
    const int nb = (bb & 31) * 4, kb = (bb >> 5) * 4;
    float4 l0 = *reinterpret_cast<const float4*>(wqs2 + (kb + 0) * 128 + nb);
    float4 l1 = *reinterpret_cast<const float4*>(wqs2 + (kb + 1) * 128 + nb);
    float4 l2 = *reinterpret_cast<const float4*>(wqs2 + (kb + 2) * 128 + nb);
    float4 l3 = *reinterpret_cast<const float4*>(wqs2 + (kb + 3) * 128 + nb);
    const float4 m0 = *reinterpret_cast<const float4*>(wks2 + (kb + 0) * 128 + nb);
    const float4 m1 = *reinterpret_cast<const float4*>(wks2 + (kb + 1) * 128 + nb);
    const float4 m2 = *reinterpret_cast<const float4*>(wks2 + (kb + 2) * 128 + nb);
    const float4 m3 = *reinterpret_cast<const float4*>(wks2 + (kb + 3) * 128 + nb);
    l0.x -= m0.x; l0.y -= m0.y; l0.z -= m0.z; l0.w -= m0.w;
    l1.x -= m1.x; l1.y -= m1.y; l1.z -= m1.z; l1.w -= m1.w;
    l2.x -= m2.x; l2.y -= m2.y; l2.z -= m2.z; l2.w -= m2.w;
    l3.x -= m3.x; l3.y -= m3.y; l3.z -= m3.z; l3.w -= m3.w;
    *reinterpret_cast<uint2*>(smW + (nb + 0) * 256 + ((kb * 2) ^ sw16(nb + 0))) = make_uint2(pk2(l0.x, l1.x), pk2(l2.x, l3.x));
    *reinterpret_cast<uint2*>(smW + (nb + 1) * 256 + ((kb * 2) ^ sw16(nb + 1))) = make_uint2(pk2(l0.y, l1.y), pk2(l2.y, l3.y));
    *reinterpret_cast<uint2*>(smW + (nb + 2) * 256 + ((kb * 2) ^ sw16(nb + 2))) = make_uint2(pk2(l0.z, l1.z), pk2(l2.z, l3.z));
    *reinterpret_cast<uint2*>(smW + (nb + 3) * 256 + ((kb * 2) ^ sw16(nb + 3))) = make_uint2(pk2(l0.w, l1.w), pk2(l2.w, l3.w));
  }
  __syncthreads();

  f32x4 acc[8];
  #pragma unroll
  for (int ni = 0; ni < 8; ++ni) acc[ni] = f32x4{0.f, 0.f, 0.f, 0.f};
  gemm128(smT, smW, wrow, lr, lg, acc);        // T1 = X @ WD2
  __syncthreads();

  #pragma unroll
  for (int ni = 0; ni < 8; ++ni)
    #pragma unroll
    for (int i = 0; i < 4; ++i) {
      const int r = wrow + lg * 4 + i;
      *reinterpret_cast<unsigned short*>(smT + r * 256 + (((ni * 16 + lr) * 2) ^ sw16(r))) = bf1(acc[ni][i]);
    }
  stageWT(w2g, smW, tid);
  __syncthreads();

  #pragma unroll
  for (int ni = 0; ni < 8; ++ni) acc[ni] = f32x4{0.f, 0.f, 0.f, 0.f};
  gemm128(smT, smW, wrow, lr, lg, acc);        // U = T1 @ fgh1
  __syncthreads();

  #pragma unroll
  for (int ni = 0; ni < 8; ++ni)
    #pragma unroll
    for (int i = 0; i < 4; ++i) {
      const int r = wrow + lg * 4 + i;
      *reinterpret_cast<unsigned short*>(smT + r * 256 + (((ni * 16 + lr) * 2) ^ sw16(r))) =
          bf1(fmaxf(acc[ni][i] + b2r[ni], 0.f));
    }
  stageWT(w3g, smW, tid);
  __syncthreads();

  #pragma unroll
  for (int ni = 0; ni < 8; ++ni) acc[ni] = f32x4{0.f, 0.f, 0.f, 0.f};
  gemm128(smT, smW, wrow, lr, lg, acc);        // P = U @ fgh2

  #pragma unroll
  for (int ni = 0; ni < 8; ++ni)
    #pragma unroll
    for (int i = 0; i < 4; ++i) {
      const ll r = blockRow + wrow + lg * 4 + i;
      P[r * 128 + ni * 16 + lr] = acc[ni][i] + b3r[ni];
    }
}

// ---------------- online softmax partial reduce ----------------
__device__ inline void omax_upd(float& m, float& s, float v, float scale) {
  if (v > m) { s = s * expf((m - v) * scale) + 1.0f; m = v; }
  else       { s += expf((v - m) * scale); }
}
__device__ inline void omax_merge(float& m, float& s, float m2, float s2, float scale) {
  if (m2 > m) { s = s * expf((m - m2) * scale) + s2; m = m2; }
  else        { s += s2 * expf((m2 - m) * scale); }
}

__global__ __launch_bounds__(256) void red1_k(const float* __restrict__ P,
                                              float* __restrict__ PM, float* __restrict__ PS) {
  const int bid = blockIdx.x;
  const int b = bid >> 7, g = (bid >> 5) & 3, seg = bid & 31;
  const int d = threadIdx.x & 127, half = threadIdx.x >> 7;
  const size_t base = (size_t)b * NN * HH + g * GS1 + d;
  float m = -3.4e38f, s = 0.f;
  const int n0 = seg * 128 + half * 64;
  for (int n = n0; n < n0 + 64; ++n)
    omax_upd(m, s, P[base + (size_t)n * HH], SC1);
  __shared__ float sm[256], ss[256];
  sm[threadIdx.x] = m; ss[threadIdx.x] = s;
  __syncthreads();
  if (half == 0) {
    omax_merge(m, s, sm[threadIdx.x + 128], ss[threadIdx.x + 128], SC1);
    const int c = b * HH + g * GS1 + d;
    PM[(size_t)seg * 2048 + c] = m;
    PS[(size_t)seg * 2048 + c] = s;
  }
}

__global__ __launch_bounds__(256) void red2_k(const float* __restrict__ A2,
                                              float* __restrict__ PM, float* __restrict__ PS) {
  const int bid = blockIdx.x;
  const int b = bid >> 5, hb = (bid >> 3) & 3, seg = bid & 7;
  const int hl = threadIdx.x & 127, half = threadIdx.x >> 7;
  const int h = hb * 128 + hl;
  const size_t base = (size_t)b * 1024 * HH + h;
  float m = -3.4e38f, s = 0.f;
  const int r0 = seg * 128 + half * 64;
  for (int r = r0; r < r0 + 64; ++r)
    omax_upd(m, s, A2[base + (size_t)r * HH], SC2);
  __shared__ float sm[256], ss[256];
  sm[threadIdx.x] = m; ss[threadIdx.x] = s;
  __syncthreads();
  if (half == 0) {
    omax_merge(m, s, sm[threadIdx.x + 128], ss[threadIdx.x + 128], SC2);
    const int c = b * HH + h;
    PM[(size_t)seg * 2048 + c] = m;
    PS[(size_t)seg * 2048 + c] = s;
  }
}

__global__ __launch_bounds__(256) void combineN_k(const float* __restrict__ PM, const float* __restrict__ PS,
                                                  float* __restrict__ Mo, float* __restrict__ Ro,
                                                  int nseg, float scale) {
  const int c = blockIdx.x * 256 + threadIdx.x;
  float m = -3.4e38f, s = 0.f;
  for (int seg = 0; seg < nseg; ++seg)
    omax_merge(m, s, PM[(size_t)seg * 2048 + c], PS[(size_t)seg * 2048 + c], scale);
  Mo[c] = m;
  Ro[c] = 1.0f / s;
}

// ---------------- KNN: one block per query, 10 extraction rounds ----------------
__global__ __launch_bounds__(256) void knn3_k(const float* __restrict__ xyz, int* __restrict__ idx) {
  const int bn = blockIdx.x;
  const int b = bn >> 12, n = bn & (NN - 1);
  const float* xb = xyz + (size_t)b * NN * 3;
  const int tid = threadIdx.x;
  const int lane = tid & 63, wid = tid >> 6;
  const float qx = xb[n * 3], qy = xb[n * 3 + 1], qz = xb[n * 3 + 2];
  const float qn2 = fmaf(qz, qz, fmaf(qy, qy, qx * qx));

  __shared__ float dists[4096];     // indexed by point id; each thread owns {i*256+tid}
  __shared__ ull wmin[4];

  ull lpack = ~0ull;
  #pragma unroll
  for (int i = 0; i < 16; ++i) {
    const int m = i * 256 + tid;
    const float px = xb[m * 3], py = xb[m * 3 + 1], pz = xb[m * 3 + 2];
    const float pn2 = fmaf(pz, pz, fmaf(py, py, px * px));
    const float dot = fmaf(qz, pz, fmaf(qy, py, qx * px));
    const float dist = fmaf(-2.f, dot, qn2 + pn2);
    dists[m] = dist;
    const ull pk = ((ull)__float_as_uint(dist) << 32) | (unsigned)m;
    lpack = pk < lpack ? pk : lpack;
  }

  for (int k = 0; k < KNN; ++k) {
    // wave-level u64 min reduce
    ull r = lpack;
    #pragma unroll
    for (int s = 1; s < 64; s <<= 1) {
      const ull o = __shfl_xor(r, s);
      r = o < r ? o : r;
    }
    if (lane == 0) wmin[wid] = r;
    __syncthreads();
    ull g = wmin[0];
    g = wmin[1] < g ? wmin[1] : g;
    g = wmin[2] < g ? wmin[2] : g;
    g = wmin[3] < g ? wmin[3] : g;
    const int gidx = (int)(unsigned)g;
    if (tid == 0) idx[(size_t)bn * KNN + k] = gidx;
    if ((gidx & 255) == tid) {
      dists[gidx] = 3.4e38f;
      ull best = ~0ull;
      #pragma unroll
      for (int i = 0; i < 16; ++i) {
        const int m = i * 256 + tid;
        const ull pk = ((ull)__float_as_uint(dists[m]) << 32) | (unsigned)m;
        best = pk < best ? pk : best;
      }
      lpack = best;
    }
    __syncthreads();
  }
}

// ---------------- pos-enc hidden mean ----------------
__global__ __launch_bounds__(256) void posenc_k(const float* __restrict__ xyz, const int* __restrict__ idx,
                                                const float* __restrict__ fd1w, const float* __restrict__ fd1b,
                                                float* __restrict__ hmean) {
  const int bn = blockIdx.x;
  const int b = bn >> 12, n = bn & (NN - 1);
  const float* xb = xyz + (size_t)b * NN * 3;
  const float qx = xb[n * 3], qy = xb[n * 3 + 1], qz = xb[n * 3 + 2];
  __shared__ float dxyz[KNN][3];
  if (threadIdx.x < KNN) {
    const int m = idx[(size_t)bn * KNN + threadIdx.x];
    dxyz[threadIdx.x][0] = qx - xb[m * 3];
    dxyz[threadIdx.x][1] = qy - xb[m * 3 + 1];
    dxyz[threadIdx.x][2] = qz - xb[m * 3 + 2];
  }
  __syncthreads();
  for (int h = threadIdx.x; h < HH; h += 256) {
    const float w0 = fd1w[h], w1 = fd1w[HH + h], w2 = fd1w[2 * HH + h], bb = fd1b[h];
    float acc = 0.f;
    #pragma unroll
    for (int k = 0; k < KNN; ++k)
      acc += fmaxf(fmaf(dxyz[k][2], w2, fmaf(dxyz[k][1], w1, dxyz[k][0] * w0)) + bb, 0.f);
    hmean[(size_t)bn * HH + h] = acc * 0.1f;
  }
}

// ---------------- res = (softmax1(P) + softmax2(A2)) * (v + posenc) ----------------
__global__ __launch_bounds__(256) void res_k(const float* __restrict__ P, const float* __restrict__ A2,
                                             const float* __restrict__ V,
                                             const float* __restrict__ M1, const float* __restrict__ R1,
                                             const float* __restrict__ M2, const float* __restrict__ R2,
                                             float* __restrict__ R) {
  const size_t i4 = (size_t)blockIdx.x * 256 + threadIdx.x;
  const size_t i = i4 * 4;
  const int b = (int)(i >> 21);
  const int n = (int)((i >> 9) & (NN - 1));
  const int h = (int)(i & (HH - 1));
  const int c = (b << 9) + h;
  const size_t j = (((size_t)b * 1024 + (n & 1023)) << 9) + h;
  const float4 p = *reinterpret_cast<const float4*>(P + i);
  const float4 a = *reinterpret_cast<const float4*>(A2 + j);
  const float4 v = *reinterpret_cast<const float4*>(V + i);
  const float4 m1 = *reinterpret_cast<const float4*>(M1 + c);
  const float4 r1 = *reinterpret_cast<const float4*>(R1 + c);
  const float4 m2 = *reinterpret_cast<const float4*>(M2 + c);
  const float4 r2 = *reinterpret_cast<const float4*>(R2 + c);
  float4 r;
  r.x = (expf((p.x - m1.x) * SC1) * r1.x + expf((a.x - m2.x) * SC2) * r2.x) * v.x;
  r.y = (expf((p.y - m1.y) * SC1) * r1.y + expf((a.y - m2.y) * SC2) * r2.y) * v.y;
  r.z = (expf((p.z - m1.z) * SC1) * r1.z + expf((a.z - m2.z) * SC2) * r2.z) * v.z;
  r.w = (expf((p.w - m1.w) * SC1) * r1.w + expf((a.w - m2.w) * SC2) * r2.w) * v.w;
  *reinterpret_cast<float4*>(R + i) = r;
}

__global__ void sub_k(const float* __restrict__ a, const float* __restrict__ b, float* __restrict__ o, int n) {
  const int i = blockIdx.x * 256 + threadIdx.x;
  if (i < n) o[i] = a[i] - b[i];
}

__global__ void copy_k(const float* __restrict__ a, float* __restrict__ o, int n) {
  const int i = blockIdx.x * 256 + threadIdx.x;
  if (i < n) o[i] = a[i];
}

extern "C" void kernel_launch(void* const* d_in, const int* in_sizes, int n_in,
                              void* d_out, int out_size, void* d_ws, size_t ws_size,
                              hipStream_t stream) {
  const float* features = (const float*)d_in[0];
  const float* xyz      = (const float*)d_in[1];
  const float* fc1_w    = (const float*)d_in[2];
  const float* fc1_b    = (const float*)d_in[3];
  const float* fc2_w    = (const float*)d_in[4];
  const float* fc2_b    = (const float*)d_in[5];
  const float* fd1_w    = (const float*)d_in[6];
  const float* fd1_b    = (const float*)d_in[7];
  const float* fd2_w    = (const float*)d_in[8];
  const float* fd2_b    = (const float*)d_in[9];
  const float* fg1_w    = (const float*)d_in[10];
  const float* fg1_b    = (const float*)d_in[11];
  const float* fg2_w    = (const float*)d_in[12];
  const float* fg2_b    = (const float*)d_in[13];
  const float* fgh1_w   = (const float*)d_in[14];
  const float* fgh1_b   = (const float*)d_in[15];
  const float* fgh2_w   = (const float*)d_in[16];
  const float* fgh2_b   = (const float*)d_in[17];
  const float* wqs      = (const float*)d_in[18];
  const float* wks      = (const float*)d_in[19];
  const float* wvs      = (const float*)d_in[20];
  const float* wqs2     = (const float*)d_in[21];
  const float* wks2     = (const float*)d_in[22];
  float* out = (float*)d_out;

  const size_t BNH = (size_t)BB * NN * HH;
  float* X   = (float*)d_ws;
  float* P   = X + BNH;
  float* Q   = P + BNH;
  float* V   = Q + BNH;
  float* S1  = V + BNH;
  float* S2  = S1 + (size_t)BB * 1024 * HH;
  float* WD  = S2 + (size_t)BB * 1024 * HH;
  int*   IDX = (int*)(WD + HH * HH);
  float* PM1 = (float*)(IDX + (size_t)BB * NN * KNN);
  float* PS1 = PM1 + 32 * 2048;
  float* PM2 = PS1 + 32 * 2048;
  float* PS2 = PM2 + 8 * 2048;
  float* M1  = PS2 + 8 * 2048;
  float* R1  = M1 + 2048;
  float* M2  = R1 + 2048;
  float* R2  = M2 + 2048;
  const size_t need = ((char*)(R2 + 2048)) - (char*)d_ws;
  if (ws_size < need) {
    fprintf(stderr, "kernel_launch: ws too small: %zu < %zu\n", ws_size, need);
    return;
  }

  sub_k<<<(HH * HH + 255) / 256, 256, 0, stream>>>(wqs, wks, WD, HH * HH);

  // x = features^T @ fc1_w + fc1_b
  mgemm_k<true, 1><<<dim3(HH / 128, NN / 128, BB), 256, 0, stream>>>(
      features, fc1_w, fc1_b, X, nullptr, NN, HH, CC, NN, (ll)CC * NN, (ll)NN * HH);

  // branch 1 fused chain -> P
  fused1_k<<<512, 512, 0, stream>>>(X, wqs2, wks2, fgh1_w, fgh1_b, fgh2_w, fgh2_b, P);
  red1_k<<<512, 256, 0, stream>>>(P, PM1, PS1);
  combineN_k<<<8, 256, 0, stream>>>(PM1, PS1, M1, R1, 32, SC1);

  // branch 2
  mgemm_k<false, 0><<<dim3(HH / 128, 1024 / 128, BB), 256, 0, stream>>>(
      X + (size_t)3072 * HH, WD, nullptr, S1, nullptr, 1024, HH, HH, HH, (ll)NN * HH, (ll)1024 * HH);
  mgemm_k<false, 2><<<dim3(HH / 128, BB * 1024 / 128, 1), 256, 0, stream>>>(
      S1, fg1_w, fg1_b, S2, nullptr, BB * 1024, HH, HH, HH, 0, 0);
  mgemm_k<false, 1><<<dim3(HH / 128, BB * 1024 / 128, 1), 256, 0, stream>>>(
      S2, fg2_w, fg2_b, S1, nullptr, BB * 1024, HH, HH, HH, 0, 0);
  red2_k<<<128, 256, 0, stream>>>(S1, PM2, PS2);
  combineN_k<<<8, 256, 0, stream>>>(PM2, PS2, M2, R2, 8, SC2);

  // v = x @ wvs
  mgemm_k<false, 0><<<dim3(HH / 128, BB * NN / 128, 1), 256, 0, stream>>>(
      X, wvs, nullptr, V, nullptr, BB * NN, HH, HH, HH, 0, 0);

  // knn + pos-enc
  knn3_k<<<BB * NN, 256, 0, stream>>>(xyz, IDX);
  posenc_k<<<BB * NN, 256, 0, stream>>>(xyz, IDX, fd1_w, fd1_b, Q);
  mgemm_k<false, 3><<<dim3(HH / 128, BB * NN / 128, 1), 256, 0, stream>>>(
      Q, fd2_w, fd2_b, V, nullptr, BB * NN, HH, HH, HH, 0, 0);

  // res -> X
  res_k<<<(int)(BNH / 4 / 256), 256, 0, stream>>>(P, S1, V, M1, R1, M2, R2, X);

  // out = swap(res @ fc2_w + fc2_b) + features
  mgemm_k<false, 4><<<dim3(CC / 128, NN / 128, BB), 256, 0, stream>>>(
      X, fc2_w, fc2_b, out, features, NN, CC, HH, HH, (ll)NN * HH, 0);

  copy_k<<<(BB * NN * 3 + 255) / 256, 256, 0, stream>>>(xyz, out + (size_t)BB * CC * NN, BB * NN * 3);
}

// Round 5
// 536.609 us; speedup vs baseline: 2.3702x; 1.0748x over previous
//
#include <hip/hip_runtime.h>
#include <cstdio>

typedef long long ll;
typedef unsigned long long ull;
typedef __bf16 bf16x8 __attribute__((ext_vector_type(8)));
typedef float f32x4 __attribute__((ext_vector_type(4)));

#define BB 4
#define NN 4096
#define CC 256
#define HH 512
#define GNUM 4
#define GS1 128
#define KNN 10

#define SC1 0.08838834764831845f   // 1/sqrt(128)
#define SC2 0.044194173824159216f  // 1/sqrt(512)

__device__ inline unsigned pk2(float x, float y) {
  unsigned a = __float_as_uint(x), b = __float_as_uint(y);
  a = (a + 0x7FFFu + ((a >> 16) & 1u)) >> 16;
  b = (b + 0x7FFFu + ((b >> 16) & 1u)) >> 16;
  return a | (b << 16);
}
__device__ inline unsigned short bf1(float x) {
  unsigned a = __float_as_uint(x);
  return (unsigned short)((a + 0x7FFFu + ((a >> 16) & 1u)) >> 16);
}
__device__ inline int sw16(int r) { return ((r ^ (r >> 3)) & 7) << 4; }

// ---------------- bf16 MFMA GEMM: C[m][n] = A[m][k] * B[k][n] ----------------
template<bool ATRANS, int EPI>
__global__ __launch_bounds__(256, 2) void mgemm_k(
    const float* __restrict__ A, const float* __restrict__ Bw,
    const float* __restrict__ bias, float* __restrict__ Cout,
    const float* __restrict__ pre,
    int M, int N, int K, int lda, ll strideA, ll strideC)
{
  const int z = blockIdx.z;
  A += (ll)z * strideA;
  const int bm = blockIdx.y * 128;
  const int bn = blockIdx.x * 128;
  __shared__ alignas(16) char smem[32768];
  char* smA = smem;
  char* smB = smem + 16384;
  const int tid = threadIdx.x;
  const int lane = tid & 63, w = tid >> 6;
  const int lr = lane & 15, lg = lane >> 4;
  const int wm = (w & 1) * 64, wn = (w >> 1) * 64;

  f32x4 acc[4][4] = {};

  for (int k0 = 0; k0 < K; k0 += 64) {
    if (!ATRANS) {
      #pragma unroll
      for (int p = 0; p < 8; ++p) {
        const int r = p * 16 + (tid >> 4);
        const int c = (tid & 15) * 4;
        const float4 v = *reinterpret_cast<const float4*>(A + (ll)(bm + r) * lda + (k0 + c));
        *reinterpret_cast<uint2*>(smA + r * 128 + ((c * 2) ^ sw16(r))) =
            make_uint2(pk2(v.x, v.y), pk2(v.z, v.w));
      }
    } else {
      #pragma unroll
      for (int p = 0; p < 2; ++p) {
        const int bb = p * 256 + tid;
        const int mb = (bb & 31) * 4, kb = (bb >> 5) * 4;
        const float4 l0 = *reinterpret_cast<const float4*>(A + (ll)(k0 + kb + 0) * lda + (bm + mb));
        const float4 l1 = *reinterpret_cast<const float4*>(A + (ll)(k0 + kb + 1) * lda + (bm + mb));
        const float4 l2 = *reinterpret_cast<const float4*>(A + (ll)(k0 + kb + 2) * lda + (bm + mb));
        const float4 l3 = *reinterpret_cast<const float4*>(A + (ll)(k0 + kb + 3) * lda + (bm + mb));
        *reinterpret_cast<uint2*>(smA + (mb + 0) * 128 + ((kb * 2) ^ sw16(mb + 0))) = make_uint2(pk2(l0.x, l1.x), pk2(l2.x, l3.x));
        *reinterpret_cast<uint2*>(smA + (mb + 1) * 128 + ((kb * 2) ^ sw16(mb + 1))) = make_uint2(pk2(l0.y, l1.y), pk2(l2.y, l3.y));
        *reinterpret_cast<uint2*>(smA + (mb + 2) * 128 + ((kb * 2) ^ sw16(mb + 2))) = make_uint2(pk2(l0.z, l1.z), pk2(l2.z, l3.z));
        *reinterpret_cast<uint2*>(smA + (mb + 3) * 128 + ((kb * 2) ^ sw16(mb + 3))) = make_uint2(pk2(l0.w, l1.w), pk2(l2.w, l3.w));
      }
    }
    #pragma unroll
    for (int p = 0; p < 2; ++p) {
      const int bb = p * 256 + tid;
      const int nb = (bb & 31) * 4, kb = (bb >> 5) * 4;
      const float4 l0 = *reinterpret_cast<const float4*>(Bw + (ll)(k0 + kb + 0) * N + (bn + nb));
      const float4 l1 = *reinterpret_cast<const float4*>(Bw + (ll)(k0 + kb + 1) * N + (bn + nb));
      const float4 l2 = *reinterpret_cast<const float4*>(Bw + (ll)(k0 + kb + 2) * N + (bn + nb));
      const float4 l3 = *reinterpret_cast<const float4*>(Bw + (ll)(k0 + kb + 3) * N + (bn + nb));
      *reinterpret_cast<uint2*>(smB + (nb + 0) * 128 + ((kb * 2) ^ sw16(nb + 0))) = make_uint2(pk2(l0.x, l1.x), pk2(l2.x, l3.x));
      *reinterpret_cast<uint2*>(smB + (nb + 1) * 128 + ((kb * 2) ^ sw16(nb + 1))) = make_uint2(pk2(l0.y, l1.y), pk2(l2.y, l3.y));
      *reinterpret_cast<uint2*>(smB + (nb + 2) * 128 + ((kb * 2) ^ sw16(nb + 2))) = make_uint2(pk2(l0.z, l1.z), pk2(l2.z, l3.z));
      *reinterpret_cast<uint2*>(smB + (nb + 3) * 128 + ((kb * 2) ^ sw16(nb + 3))) = make_uint2(pk2(l0.w, l1.w), pk2(l2.w, l3.w));
    }
    __syncthreads();

    #pragma unroll
    for (int ks = 0; ks < 2; ++ks) {
      bf16x8 af[4], bfr[4];
      #pragma unroll
      for (int mi = 0; mi < 4; ++mi) {
        const int r = wm + mi * 16 + lr;
        af[mi] = *reinterpret_cast<const bf16x8*>(smA + r * 128 + ((((ks << 2) + lg) << 4) ^ sw16(r)));
      }
      #pragma unroll
      for (int ni = 0; ni < 4; ++ni) {
        const int r = wn + ni * 16 + lr;
        bfr[ni] = *reinterpret_cast<const bf16x8*>(smB + r * 128 + ((((ks << 2) + lg) << 4) ^ sw16(r)));
      }
      #pragma unroll
      for (int mi = 0; mi < 4; ++mi)
        #pragma unroll
        for (int ni = 0; ni < 4; ++ni)
          acc[mi][ni] = __builtin_amdgcn_mfma_f32_16x16x32_bf16(af[mi], bfr[ni], acc[mi][ni], 0, 0, 0);
    }
    __syncthreads();
  }

  const ll cb = (ll)z * strideC;
  #pragma unroll
  for (int ni = 0; ni < 4; ++ni) {
    const int col = bn + wn + ni * 16 + lr;
    const float bv = (EPI != 0) ? bias[col] : 0.f;
    #pragma unroll
    for (int mi = 0; mi < 4; ++mi) {
      const int row0 = bm + wm + mi * 16 + lg * 4;
      if (EPI == 4) {
        const size_t o = ((size_t)z * N + col) * (size_t)M + row0;
        const float4 pv = *reinterpret_cast<const float4*>(pre + o);
        float4 r;
        r.x = acc[mi][ni][0] + bv + pv.x;
        r.y = acc[mi][ni][1] + bv + pv.y;
        r.z = acc[mi][ni][2] + bv + pv.z;
        r.w = acc[mi][ni][3] + bv + pv.w;
        *reinterpret_cast<float4*>(Cout + o) = r;
      } else {
        #pragma unroll
        for (int i = 0; i < 4; ++i) {
          float val = acc[mi][ni][i] + bv;
          if (EPI == 2) val = fmaxf(val, 0.f);
          if (EPI == 3) Cout[cb + (ll)(row0 + i) * N + col] += val;
          else          Cout[cb + (ll)(row0 + i) * N + col] = val;
        }
      }
    }
  }
}

// ---------------- fused branch-1 chain: P = (relu((X@WD2)@fgh1+b1))@fgh2+b2 ----------------
__device__ __forceinline__ void gemm128(const char* smA, const char* smW, int wrow, int lr, int lg,
                                        f32x4 acc[8]) {
  #pragma unroll
  for (int ks = 0; ks < 4; ++ks) {
    const int koff = (ks * 4 + lg) * 16;
    const int ra = wrow + lr;
    const bf16x8 a = *reinterpret_cast<const bf16x8*>(smA + ra * 256 + (koff ^ sw16(ra)));
    #pragma unroll
    for (int ni = 0; ni < 8; ++ni) {
      const int rn = ni * 16 + lr;
      const bf16x8 b = *reinterpret_cast<const bf16x8*>(smW + rn * 256 + (koff ^ sw16(rn)));
      acc[ni] = __builtin_amdgcn_mfma_f32_16x16x32_bf16(a, b, acc[ni], 0, 0, 0);
    }
  }
}

__device__ __forceinline__ void stageWT(const float* __restrict__ W, char* smW, int tid) {
  #pragma unroll
  for (int p = 0; p < 2; ++p) {
    const int bb = p * 512 + tid;
    const int nb = (bb & 31) * 4, kb = (bb >> 5) * 4;
    const float4 l0 = *reinterpret_cast<const float4*>(W + (kb + 0) * 128 + nb);
    const float4 l1 = *reinterpret_cast<const float4*>(W + (kb + 1) * 128 + nb);
    const float4 l2 = *reinterpret_cast<const float4*>(W + (kb + 2) * 128 + nb);
    const float4 l3 = *reinterpret_cast<const float4*>(W + (kb + 3) * 128 + nb);
    *reinterpret_cast<uint2*>(smW + (nb + 0) * 256 + ((kb * 2) ^ sw16(nb + 0))) = make_uint2(pk2(l0.x, l1.x), pk2(l2.x, l3.x));
    *reinterpret_cast<uint2*>(smW + (nb + 1) * 256 + ((kb * 2) ^ sw16(nb + 1))) = make_uint2(pk2(l0.y, l1.y), pk2(l2.y, l3.y));
    *reinterpret_cast<uint2*>(smW + (nb + 2) * 256 + ((kb * 2) ^ sw16(nb + 2))) = make_uint2(pk2(l0.z, l1.z), pk2(l2.z, l3.z));
    *reinterpret_cast<uint2*>(smW + (nb + 3) * 256 + ((kb * 2) ^ sw16(nb + 3))) = make_uint2(pk2(l0.w, l1.w), pk2(l2.w, l3.w));
  }
}

__global__ __launch_bounds__(512, 4) void fused1_k(
    const float* __restrict__ X,
    const float* __restrict__ wqs2, const float* __restrict__ wks2,
    const float* __restrict__ w2g, const float* __restrict__ b2g,
    const float* __restrict__ w3g, const float* __restrict__ b3g,
    float* __restrict__ P)
{
  __shared__ alignas(16) char smT[32768];
  __shared__ alignas(16) char smW[32768];
  const int tid = threadIdx.x;
  const int lane = tid & 63, w = tid >> 6;
  const int lr = lane & 15, lg = lane >> 4;
  const int wrow = w * 16;
  const ll blockRow = (ll)blockIdx.x * 128;
  const float* Xb = X + blockRow * 128;

  float b2r[8], b3r[8];
  #pragma unroll
  for (int ni = 0; ni < 8; ++ni) { b2r[ni] = b2g[ni * 16 + lr]; b3r[ni] = b3g[ni * 16 + lr]; }

  #pragma unroll
  for (int p = 0; p < 8; ++p) {
    const int i = p * 512 + tid;
    const int r = i >> 5, c4 = (i & 31) * 4;
    const float4 v = *reinterpret_cast<const float4*>(Xb + (ll)r * 128 + c4);
    *reinterpret_cast<uint2*>(smT + r * 256 + ((c4 * 2) ^ sw16(r))) =
        make_uint2(pk2(v.x, v.y), pk2(v.z, v.w));
  }
  #pragma unroll
  for (int p = 0; p < 2; ++p) {
    const int bb = p * 512 + tid;
    const int nb = (bb & 31) * 4, kb = (bb >> 5) * 4;
    float4 l0 = *reinterpret_cast<const float4*>(wqs2 + (kb + 0) * 128 + nb);
    float4 l1 = *reinterpret_cast<const float4*>(wqs2 + (kb + 1) * 128 + nb);
    float4 l2 = *reinterpret_cast<const float4*>(wqs2 + (kb + 2) * 128 + nb);
    float4 l3 = *reinterpret_cast<const float4*>(wqs2 + (kb + 3) * 128 + nb);
    const float4 m0 = *reinterpret_cast<const float4*>(wks2 + (kb + 0) * 128 + nb);
    const float4 m1 = *reinterpret_cast<const float4*>(wks2 + (kb + 1) * 128 + nb);
    const float4 m2 = *reinterpret_cast<const float4*>(wks2 + (kb + 2) * 128 + nb);
    const float4 m3 = *reinterpret_cast<const float4*>(wks2 + (kb + 3) * 128 + nb);
    l0.x -= m0.x; l0.y -= m0.y; l0.z -= m0.z; l0.w -= m0.w;
    l1.x -= m1.x; l1.y -= m1.y; l1.z -= m1.z; l1.w -= m1.w;
    l2.x -= m2.x; l2.y -= m2.y; l2.z -= m2.z; l2.w -= m2.w;
    l3.x -= m3.x; l3.y -= m3.y; l3.z -= m3.z; l3.w -= m3.w;
    *reinterpret_cast<uint2*>(smW + (nb + 0) * 256 + ((kb * 2) ^ sw16(nb + 0))) = make_uint2(pk2(l0.x, l1.x), pk2(l2.x, l3.x));
    *reinterpret_cast<uint2*>(smW + (nb + 1) * 256 + ((kb * 2) ^ sw16(nb + 1))) = make_uint2(pk2(l0.y, l1.y), pk2(l2.y, l3.y));
    *reinterpret_cast<uint2*>(smW + (nb + 2) * 256 + ((kb * 2) ^ sw16(nb + 2))) = make_uint2(pk2(l0.z, l1.z), pk2(l2.z, l3.z));
    *reinterpret_cast<uint2*>(smW + (nb + 3) * 256 + ((kb * 2) ^ sw16(nb + 3))) = make_uint2(pk2(l0.w, l1.w), pk2(l2.w, l3.w));
  }
  __syncthreads();

  f32x4 acc[8];
  #pragma unroll
  for (int ni = 0; ni < 8; ++ni) acc[ni] = f32x4{0.f, 0.f, 0.f, 0.f};
  gemm128(smT, smW, wrow, lr, lg, acc);        // T1 = X @ WD2
  __syncthreads();

  #pragma unroll
  for (int ni = 0; ni < 8; ++ni)
    #pragma unroll
    for (int i = 0; i < 4; ++i) {
      const int r = wrow + lg * 4 + i;
      *reinterpret_cast<unsigned short*>(smT + r * 256 + (((ni * 16 + lr) * 2) ^ sw16(r))) = bf1(acc[ni][i]);
    }
  stageWT(w2g, smW, tid);
  __syncthreads();

  #pragma unroll
  for (int ni = 0; ni < 8; ++ni) acc[ni] = f32x4{0.f, 0.f, 0.f, 0.f};
  gemm128(smT, smW, wrow, lr, lg, acc);        // U = T1 @ fgh1
  __syncthreads();

  #pragma unroll
  for (int ni = 0; ni < 8; ++ni)
    #pragma unroll
    for (int i = 0; i < 4; ++i) {
      const int r = wrow + lg * 4 + i;
      *reinterpret_cast<unsigned short*>(smT + r * 256 + (((ni * 16 + lr) * 2) ^ sw16(r))) =
          bf1(fmaxf(acc[ni][i] + b2r[ni], 0.f));
    }
  stageWT(w3g, smW, tid);
  __syncthreads();

  #pragma unroll
  for (int ni = 0; ni < 8; ++ni) acc[ni] = f32x4{0.f, 0.f, 0.f, 0.f};
  gemm128(smT, smW, wrow, lr, lg, acc);        // P = U @ fgh2

  #pragma unroll
  for (int ni = 0; ni < 8; ++ni)
    #pragma unroll
    for (int i = 0; i < 4; ++i) {
      const ll r = blockRow + wrow + lg * 4 + i;
      P[r * 128 + ni * 16 + lr] = acc[ni][i] + b3r[ni];
    }
}

// ---------------- online softmax partial reduce ----------------
__device__ inline void omax_upd(float& m, float& s, float v, float scale) {
  if (v > m) { s = s * expf((m - v) * scale) + 1.0f; m = v; }
  else       { s += expf((v - m) * scale); }
}
__device__ inline void omax_merge(float& m, float& s, float m2, float s2, float scale) {
  if (m2 > m) { s = s * expf((m - m2) * scale) + s2; m = m2; }
  else        { s += s2 * expf((m2 - m) * scale); }
}

__global__ __launch_bounds__(256) void red1_k(const float* __restrict__ P,
                                              float* __restrict__ PM, float* __restrict__ PS) {
  const int bid = blockIdx.x;
  const int b = bid >> 7, g = (bid >> 5) & 3, seg = bid & 31;
  const int d = threadIdx.x & 127, half = threadIdx.x >> 7;
  const size_t base = (size_t)b * NN * HH + g * GS1 + d;
  float m = -3.4e38f, s = 0.f;
  const int n0 = seg * 128 + half * 64;
  for (int n = n0; n < n0 + 64; ++n)
    omax_upd(m, s, P[base + (size_t)n * HH], SC1);
  __shared__ float sm[256], ss[256];
  sm[threadIdx.x] = m; ss[threadIdx.x] = s;
  __syncthreads();
  if (half == 0) {
    omax_merge(m, s, sm[threadIdx.x + 128], ss[threadIdx.x + 128], SC1);
    const int c = b * HH + g * GS1 + d;
    PM[(size_t)seg * 2048 + c] = m;
    PS[(size_t)seg * 2048 + c] = s;
  }
}

__global__ __launch_bounds__(256) void red2_k(const float* __restrict__ A2,
                                              float* __restrict__ PM, float* __restrict__ PS) {
  const int bid = blockIdx.x;
  const int b = bid >> 5, hb = (bid >> 3) & 3, seg = bid & 7;
  const int hl = threadIdx.x & 127, half = threadIdx.x >> 7;
  const int h = hb * 128 + hl;
  const size_t base = (size_t)b * 1024 * HH + h;
  float m = -3.4e38f, s = 0.f;
  const int r0 = seg * 128 + half * 64;
  for (int r = r0; r < r0 + 64; ++r)
    omax_upd(m, s, A2[base + (size_t)r * HH], SC2);
  __shared__ float sm[256], ss[256];
  sm[threadIdx.x] = m; ss[threadIdx.x] = s;
  __syncthreads();
  if (half == 0) {
    omax_merge(m, s, sm[threadIdx.x + 128], ss[threadIdx.x + 128], SC2);
    const int c = b * HH + h;
    PM[(size_t)seg * 2048 + c] = m;
    PS[(size_t)seg * 2048 + c] = s;
  }
}

__global__ __launch_bounds__(256) void combineN_k(const float* __restrict__ PM, const float* __restrict__ PS,
                                                  float* __restrict__ Mo, float* __restrict__ Ro,
                                                  int nseg, float scale) {
  const int c = blockIdx.x * 256 + threadIdx.x;
  float m = -3.4e38f, s = 0.f;
  for (int seg = 0; seg < nseg; ++seg)
    omax_merge(m, s, PM[(size_t)seg * 2048 + c], PS[(size_t)seg * 2048 + c], scale);
  Mo[c] = m;
  Ro[c] = 1.0f / s;
}

// ---------------- KNN: histogram select, one block per query ----------------
__global__ __launch_bounds__(256) void knn4_k(const float* __restrict__ xyz, int* __restrict__ idx) {
  const int bn = blockIdx.x;
  const int b = bn >> 12, n = bn & (NN - 1);
  const float* xb = xyz + (size_t)b * NN * 3;
  const int tid = threadIdx.x;
  const float qx = xb[n * 3], qy = xb[n * 3 + 1], qz = xb[n * 3 + 2];
  const float qn2 = fmaf(qz, qz, fmaf(qy, qy, qx * qx));

  __shared__ unsigned short q16[4096];
  __shared__ unsigned hist[256], hist2[256];
  __shared__ unsigned short cand[64];
  __shared__ int sB1, sCB, sT, sCnt;

  hist[tid] = 0; hist2[tid] = 0;
  if (tid == 0) sCnt = 0;
  __syncthreads();

  // phase A: distances -> monotonic 16-bit keys + level-1 histogram
  #pragma unroll
  for (int i = 0; i < 16; ++i) {
    const int m = i * 256 + tid;
    const float px = xb[m * 3], py = xb[m * 3 + 1], pz = xb[m * 3 + 2];
    const float pn2 = fmaf(pz, pz, fmaf(py, py, px * px));
    const float dot = fmaf(qz, pz, fmaf(qy, py, qx * px));
    const float dist = fmaf(-2.f, dot, qn2 + pn2);
    const float x = sqrtf(fmaxf(dist, 0.f)) * 37632.0f;  // 147*256, max ~65200
    const int q = (int)fminf(x, 65535.0f);
    q16[m] = (unsigned short)q;
    atomicAdd(&hist[q >> 8], 1u);
  }
  __syncthreads();

  // phase B: level-1 scan (wave 0): find bin with cumulative >= 10
  if (tid < 64) {
    const int lane = tid;
    unsigned h0 = hist[lane * 4], h1 = hist[lane * 4 + 1], h2 = hist[lane * 4 + 2], h3 = hist[lane * 4 + 3];
    unsigned s = h0 + h1 + h2 + h3;
    unsigned cum = s;
    #pragma unroll
    for (int off = 1; off < 64; off <<= 1) {
      const unsigned t = __shfl_up(cum, off);
      if (lane >= off) cum += t;
    }
    const ull bal = __ballot(cum >= 10u);
    const int first = __ffsll((ll)bal) - 1;
    if (lane == first) {
      unsigned c = cum - s;  // exclusive before this lane's 4 bins
      int bin = lane * 4;
      unsigned hh[4] = {h0, h1, h2, h3};
      #pragma unroll
      for (int j = 0; j < 4; ++j) {
        if (c + hh[j] >= 10u) { sB1 = bin + j; sCB = (int)c; break; }
        c += hh[j];
      }
    }
  }
  __syncthreads();

  // phase C: level-2 histogram within bin B1
  const int B1 = sB1, CB = sCB;
  #pragma unroll
  for (int i = 0; i < 16; ++i) {
    const int m = i * 256 + tid;
    const unsigned q = q16[m];
    if ((int)(q >> 8) == B1) atomicAdd(&hist2[q & 255u], 1u);
  }
  __syncthreads();

  // phase B2: level-2 scan (wave 0): target K' = 10 - CB
  if (tid < 64) {
    const int lane = tid;
    const unsigned K2 = (unsigned)(10 - CB);
    unsigned h0 = hist2[lane * 4], h1 = hist2[lane * 4 + 1], h2 = hist2[lane * 4 + 2], h3 = hist2[lane * 4 + 3];
    unsigned s = h0 + h1 + h2 + h3;
    unsigned cum = s;
    #pragma unroll
    for (int off = 1; off < 64; off <<= 1) {
      const unsigned t = __shfl_up(cum, off);
      if (lane >= off) cum += t;
    }
    const ull bal = __ballot(cum >= K2);
    const int first = __ffsll((ll)bal) - 1;
    if (lane == first) {
      unsigned c = cum - s;
      int bin = lane * 4;
      unsigned hh[4] = {h0, h1, h2, h3};
      #pragma unroll
      for (int j = 0; j < 4; ++j) {
        if (c + hh[j] >= K2) { sT = (B1 << 8) | (bin + j); break; }
        c += hh[j];
      }
    }
  }
  __syncthreads();

  // phase D: gather candidates with q16 <= T
  const unsigned T = (unsigned)sT;
  #pragma unroll
  for (int i = 0; i < 16; ++i) {
    const int m = i * 256 + tid;
    if ((unsigned)q16[m] <= T) {
      const int slot = atomicAdd(&sCnt, 1);
      if (slot < 64) cand[slot] = (unsigned short)m;
    }
  }
  __syncthreads();

  // phase E: wave 0 recomputes exact keys, bitonic sorts 64, writes top-10
  if (tid < 64) {
    const int lane = tid;
    const int c = sCnt < 64 ? sCnt : 64;
    ull v = ~0ull;
    if (lane < c) {
      const int m = cand[lane];
      const float px = xb[m * 3], py = xb[m * 3 + 1], pz = xb[m * 3 + 2];
      const float pn2 = fmaf(pz, pz, fmaf(py, py, px * px));
      const float dot = fmaf(qz, pz, fmaf(qy, py, qx * px));
      const float dist = fmaf(-2.f, dot, qn2 + pn2);
      const unsigned u = __float_as_uint(dist);
      const unsigned key = u ^ (unsigned)(((int)u >> 31) | 0x80000000);
      v = ((ull)key << 12) | (unsigned)m;
    }
    #pragma unroll
    for (int k = 2; k <= 64; k <<= 1) {
      #pragma unroll
      for (int j = k >> 1; j > 0; j >>= 1) {
        const ull o = __shfl_xor(v, j);
        const bool up = ((lane & k) == 0);
        const bool lower = ((lane & j) == 0);
        const bool keepMin = (lower == up);
        const bool oLess = o < v;
        v = (keepMin == oLess) ? o : v;
      }
    }
    if (lane < KNN) idx[(size_t)bn * KNN + lane] = (int)(v & 0xFFFull);
  }
}

// ---------------- pos-enc hidden mean ----------------
__global__ __launch_bounds__(256) void posenc_k(const float* __restrict__ xyz, const int* __restrict__ idx,
                                                const float* __restrict__ fd1w, const float* __restrict__ fd1b,
                                                float* __restrict__ hmean) {
  const int bn = blockIdx.x;
  const int b = bn >> 12, n = bn & (NN - 1);
  const float* xb = xyz + (size_t)b * NN * 3;
  const float qx = xb[n * 3], qy = xb[n * 3 + 1], qz = xb[n * 3 + 2];
  __shared__ float dxyz[KNN][3];
  if (threadIdx.x < KNN) {
    const int m = idx[(size_t)bn * KNN + threadIdx.x];
    dxyz[threadIdx.x][0] = qx - xb[m * 3];
    dxyz[threadIdx.x][1] = qy - xb[m * 3 + 1];
    dxyz[threadIdx.x][2] = qz - xb[m * 3 + 2];
  }
  __syncthreads();
  for (int h = threadIdx.x; h < HH; h += 256) {
    const float w0 = fd1w[h], w1 = fd1w[HH + h], w2 = fd1w[2 * HH + h], bb = fd1b[h];
    float acc = 0.f;
    #pragma unroll
    for (int k = 0; k < KNN; ++k)
      acc += fmaxf(fmaf(dxyz[k][2], w2, fmaf(dxyz[k][1], w1, dxyz[k][0] * w0)) + bb, 0.f);
    hmean[(size_t)bn * HH + h] = acc * 0.1f;
  }
}

// ---------------- res = (softmax1(P) + softmax2(A2)) * (v + posenc) ----------------
__global__ __launch_bounds__(256) void res_k(const float* __restrict__ P, const float* __restrict__ A2,
                                             const float* __restrict__ V,
                                             const float* __restrict__ M1, const float* __restrict__ R1,
                                             const float* __restrict__ M2, const float* __restrict__ R2,
                                             float* __restrict__ R) {
  const size_t i4 = (size_t)blockIdx.x * 256 + threadIdx.x;
  const size_t i = i4 * 4;
  const int b = (int)(i >> 21);
  const int n = (int)((i >> 9) & (NN - 1));
  const int h = (int)(i & (HH - 1));
  const int c = (b << 9) + h;
  const size_t j = (((size_t)b * 1024 + (n & 1023)) << 9) + h;
  const float4 p = *reinterpret_cast<const float4*>(P + i);
  const float4 a = *reinterpret_cast<const float4*>(A2 + j);
  const float4 v = *reinterpret_cast<const float4*>(V + i);
  const float4 m1 = *reinterpret_cast<const float4*>(M1 + c);
  const float4 r1 = *reinterpret_cast<const float4*>(R1 + c);
  const float4 m2 = *reinterpret_cast<const float4*>(M2 + c);
  const float4 r2 = *reinterpret_cast<const float4*>(R2 + c);
  float4 r;
  r.x = (expf((p.x - m1.x) * SC1) * r1.x + expf((a.x - m2.x) * SC2) * r2.x) * v.x;
  r.y = (expf((p.y - m1.y) * SC1) * r1.y + expf((a.y - m2.y) * SC2) * r2.y) * v.y;
  r.z = (expf((p.z - m1.z) * SC1) * r1.z + expf((a.z - m2.z) * SC2) * r2.z) * v.z;
  r.w = (expf((p.w - m1.w) * SC1) * r1.w + expf((a.w - m2.w) * SC2) * r2.w) * v.w;
  *reinterpret_cast<float4*>(R + i) = r;
}

__global__ void sub_k(const float* __restrict__ a, const float* __restrict__ b, float* __restrict__ o, int n) {
  const int i = blockIdx.x * 256 + threadIdx.x;
  if (i < n) o[i] = a[i] - b[i];
}

__global__ void copy_k(const float* __restrict__ a, float* __restrict__ o, int n) {
  const int i = blockIdx.x * 256 + threadIdx.x;
  if (i < n) o[i] = a[i];
}

extern "C" void kernel_launch(void* const* d_in, const int* in_sizes, int n_in,
                              void* d_out, int out_size, void* d_ws, size_t ws_size,
                              hipStream_t stream) {
  const float* features = (const float*)d_in[0];
  const float* xyz      = (const float*)d_in[1];
  const float* fc1_w    = (const float*)d_in[2];
  const float* fc1_b    = (const float*)d_in[3];
  const float* fc2_w    = (const float*)d_in[4];
  const float* fc2_b    = (const float*)d_in[5];
  const float* fd1_w    = (const float*)d_in[6];
  const float* fd1_b    = (const float*)d_in[7];
  const float* fd2_w    = (const float*)d_in[8];
  const float* fd2_b    = (const float*)d_in[9];
  const float* fg1_w    = (const float*)d_in[10];
  const float* fg1_b    = (const float*)d_in[11];
  const float* fg2_w    = (const float*)d_in[12];
  const float* fg2_b    = (const float*)d_in[13];
  const float* fgh1_w   = (const float*)d_in[14];
  const float* fgh1_b   = (const float*)d_in[15];
  const float* fgh2_w   = (const float*)d_in[16];
  const float* fgh2_b   = (const float*)d_in[17];
  const float* wqs      = (const float*)d_in[18];
  const float* wks      = (const float*)d_in[19];
  const float* wvs      = (const float*)d_in[20];
  const float* wqs2     = (const float*)d_in[21];
  const float* wks2     = (const float*)d_in[22];
  float* out = (float*)d_out;

  const size_t BNH = (size_t)BB * NN * HH;
  float* X   = (float*)d_ws;
  float* P   = X + BNH;
  float* Q   = P + BNH;
  float* V   = Q + BNH;
  float* S1  = V + BNH;
  float* S2  = S1 + (size_t)BB * 1024 * HH;
  float* WD  = S2 + (size_t)BB * 1024 * HH;
  int*   IDX = (int*)(WD + HH * HH);
  float* PM1 = (float*)(IDX + (size_t)BB * NN * KNN);
  float* PS1 = PM1 + 32 * 2048;
  float* PM2 = PS1 + 32 * 2048;
  float* PS2 = PM2 + 8 * 2048;
  float* M1  = PS2 + 8 * 2048;
  float* R1  = M1 + 2048;
  float* M2  = R1 + 2048;
  float* R2  = M2 + 2048;
  const size_t need = ((char*)(R2 + 2048)) - (char*)d_ws;
  if (ws_size < need) {
    fprintf(stderr, "kernel_launch: ws too small: %zu < %zu\n", ws_size, need);
    return;
  }

  sub_k<<<(HH * HH + 255) / 256, 256, 0, stream>>>(wqs, wks, WD, HH * HH);

  // x = features^T @ fc1_w + fc1_b
  mgemm_k<true, 1><<<dim3(HH / 128, NN / 128, BB), 256, 0, stream>>>(
      features, fc1_w, fc1_b, X, nullptr, NN, HH, CC, NN, (ll)CC * NN, (ll)NN * HH);

  // branch 1 fused chain -> P
  fused1_k<<<512, 512, 0, stream>>>(X, wqs2, wks2, fgh1_w, fgh1_b, fgh2_w, fgh2_b, P);
  red1_k<<<512, 256, 0, stream>>>(P, PM1, PS1);
  combineN_k<<<8, 256, 0, stream>>>(PM1, PS1, M1, R1, 32, SC1);

  // branch 2
  mgemm_k<false, 0><<<dim3(HH / 128, 1024 / 128, BB), 256, 0, stream>>>(
      X + (size_t)3072 * HH, WD, nullptr, S1, nullptr, 1024, HH, HH, HH, (ll)NN * HH, (ll)1024 * HH);
  mgemm_k<false, 2><<<dim3(HH / 128, BB * 1024 / 128, 1), 256, 0, stream>>>(
      S1, fg1_w, fg1_b, S2, nullptr, BB * 1024, HH, HH, HH, 0, 0);
  mgemm_k<false, 1><<<dim3(HH / 128, BB * 1024 / 128, 1), 256, 0, stream>>>(
      S2, fg2_w, fg2_b, S1, nullptr, BB * 1024, HH, HH, HH, 0, 0);
  red2_k<<<128, 256, 0, stream>>>(S1, PM2, PS2);
  combineN_k<<<8, 256, 0, stream>>>(PM2, PS2, M2, R2, 8, SC2);

  // v = x @ wvs
  mgemm_k<false, 0><<<dim3(HH / 128, BB * NN / 128, 1), 256, 0, stream>>>(
      X, wvs, nullptr, V, nullptr, BB * NN, HH, HH, HH, 0, 0);

  // knn + pos-enc
  knn4_k<<<BB * NN, 256, 0, stream>>>(xyz, IDX);
  posenc_k<<<BB * NN, 256, 0, stream>>>(xyz, IDX, fd1_w, fd1_b, Q);
  mgemm_k<false, 3><<<dim3(HH / 128, BB * NN / 128, 1), 256, 0, stream>>>(
      Q, fd2_w, fd2_b, V, nullptr, BB * NN, HH, HH, HH, 0, 0);

  // res -> X
  res_k<<<(int)(BNH / 4 / 256), 256, 0, stream>>>(P, S1, V, M1, R1, M2, R2, X);

  // out = swap(res @ fc2_w + fc2_b) + features
  mgemm_k<false, 4><<<dim3(CC / 128, NN / 128, BB), 256, 0, stream>>>(
      X, fc2_w, fc2_b, out, features, NN, CC, HH, HH, (ll)NN * HH, 0);

  copy_k<<<(BB * NN * 3 + 255) / 256, 256, 0, stream>>>(xyz, out + (size_t)BB * CC * NN, BB * NN * 3);
}

// Round 6
// 465.780 us; speedup vs baseline: 2.7306x; 1.1521x over previous
//
#include <hip/hip_runtime.h>
#include <cstdio>

typedef long long ll;
typedef unsigned long long ull;
typedef __bf16 bf16x8 __attribute__((ext_vector_type(8)));
typedef float f32x4 __attribute__((ext_vector_type(4)));

#define BB 4
#define NN 4096
#define CC 256
#define HH 512
#define GNUM 4
#define GS1 128
#define KNN 10

#define SC1 0.08838834764831845f   // 1/sqrt(128)
#define SC2 0.044194173824159216f  // 1/sqrt(512)

__device__ inline unsigned pk2(float x, float y) {
  unsigned a = __float_as_uint(x), b = __float_as_uint(y);
  a = (a + 0x7FFFu + ((a >> 16) & 1u)) >> 16;
  b = (b + 0x7FFFu + ((b >> 16) & 1u)) >> 16;
  return a | (b << 16);
}
__device__ inline unsigned short bf1(float x) {
  unsigned a = __float_as_uint(x);
  return (unsigned short)((a + 0x7FFFu + ((a >> 16) & 1u)) >> 16);
}
__device__ inline int sw16(int r) { return ((r ^ (r >> 3)) & 7) << 4; }

// ---------------- bf16 MFMA GEMM: C[m][n] = A[m][k] * B[k][n] ----------------
template<bool ATRANS, int EPI>
__global__ __launch_bounds__(256, 2) void mgemm_k(
    const float* __restrict__ A, const float* __restrict__ Bw,
    const float* __restrict__ bias, float* __restrict__ Cout,
    const float* __restrict__ pre,
    int M, int N, int K, int lda, ll strideA, ll strideC)
{
  const int z = blockIdx.z;
  A += (ll)z * strideA;
  const int bm = blockIdx.y * 128;
  const int bn = blockIdx.x * 128;
  __shared__ alignas(16) char smem[32768];
  char* smA = smem;
  char* smB = smem + 16384;
  const int tid = threadIdx.x;
  const int lane = tid & 63, w = tid >> 6;
  const int lr = lane & 15, lg = lane >> 4;
  const int wm = (w & 1) * 64, wn = (w >> 1) * 64;

  f32x4 acc[4][4] = {};

  for (int k0 = 0; k0 < K; k0 += 64) {
    if (!ATRANS) {
      #pragma unroll
      for (int p = 0; p < 8; ++p) {
        const int r = p * 16 + (tid >> 4);
        const int c = (tid & 15) * 4;
        const float4 v = *reinterpret_cast<const float4*>(A + (ll)(bm + r) * lda + (k0 + c));
        *reinterpret_cast<uint2*>(smA + r * 128 + ((c * 2) ^ sw16(r))) =
            make_uint2(pk2(v.x, v.y), pk2(v.z, v.w));
      }
    } else {
      #pragma unroll
      for (int p = 0; p < 2; ++p) {
        const int bb = p * 256 + tid;
        const int mb = (bb & 31) * 4, kb = (bb >> 5) * 4;
        const float4 l0 = *reinterpret_cast<const float4*>(A + (ll)(k0 + kb + 0) * lda + (bm + mb));
        const float4 l1 = *reinterpret_cast<const float4*>(A + (ll)(k0 + kb + 1) * lda + (bm + mb));
        const float4 l2 = *reinterpret_cast<const float4*>(A + (ll)(k0 + kb + 2) * lda + (bm + mb));
        const float4 l3 = *reinterpret_cast<const float4*>(A + (ll)(k0 + kb + 3) * lda + (bm + mb));
        *reinterpret_cast<uint2*>(smA + (mb + 0) * 128 + ((kb * 2) ^ sw16(mb + 0))) = make_uint2(pk2(l0.x, l1.x), pk2(l2.x, l3.x));
        *reinterpret_cast<uint2*>(smA + (mb + 1) * 128 + ((kb * 2) ^ sw16(mb + 1))) = make_uint2(pk2(l0.y, l1.y), pk2(l2.y, l3.y));
        *reinterpret_cast<uint2*>(smA + (mb + 2) * 128 + ((kb * 2) ^ sw16(mb + 2))) = make_uint2(pk2(l0.z, l1.z), pk2(l2.z, l3.z));
        *reinterpret_cast<uint2*>(smA + (mb + 3) * 128 + ((kb * 2) ^ sw16(mb + 3))) = make_uint2(pk2(l0.w, l1.w), pk2(l2.w, l3.w));
      }
    }
    #pragma unroll
    for (int p = 0; p < 2; ++p) {
      const int bb = p * 256 + tid;
      const int nb = (bb & 31) * 4, kb = (bb >> 5) * 4;
      const float4 l0 = *reinterpret_cast<const float4*>(Bw + (ll)(k0 + kb + 0) * N + (bn + nb));
      const float4 l1 = *reinterpret_cast<const float4*>(Bw + (ll)(k0 + kb + 1) * N + (bn + nb));
      const float4 l2 = *reinterpret_cast<const float4*>(Bw + (ll)(k0 + kb + 2) * N + (bn + nb));
      const float4 l3 = *reinterpret_cast<const float4*>(Bw + (ll)(k0 + kb + 3) * N + (bn + nb));
      *reinterpret_cast<uint2*>(smB + (nb + 0) * 128 + ((kb * 2) ^ sw16(nb + 0))) = make_uint2(pk2(l0.x, l1.x), pk2(l2.x, l3.x));
      *reinterpret_cast<uint2*>(smB + (nb + 1) * 128 + ((kb * 2) ^ sw16(nb + 1))) = make_uint2(pk2(l0.y, l1.y), pk2(l2.y, l3.y));
      *reinterpret_cast<uint2*>(smB + (nb + 2) * 128 + ((kb * 2) ^ sw16(nb + 2))) = make_uint2(pk2(l0.z, l1.z), pk2(l2.z, l3.z));
      *reinterpret_cast<uint2*>(smB + (nb + 3) * 128 + ((kb * 2) ^ sw16(nb + 3))) = make_uint2(pk2(l0.w, l1.w), pk2(l2.w, l3.w));
    }
    __syncthreads();

    #pragma unroll
    for (int ks = 0; ks < 2; ++ks) {
      bf16x8 af[4], bfr[4];
      #pragma unroll
      for (int mi = 0; mi < 4; ++mi) {
        const int r = wm + mi * 16 + lr;
        af[mi] = *reinterpret_cast<const bf16x8*>(smA + r * 128 + ((((ks << 2) + lg) << 4) ^ sw16(r)));
      }
      #pragma unroll
      for (int ni = 0; ni < 4; ++ni) {
        const int r = wn + ni * 16 + lr;
        bfr[ni] = *reinterpret_cast<const bf16x8*>(smB + r * 128 + ((((ks << 2) + lg) << 4) ^ sw16(r)));
      }
      #pragma unroll
      for (int mi = 0; mi < 4; ++mi)
        #pragma unroll
        for (int ni = 0; ni < 4; ++ni)
          acc[mi][ni] = __builtin_amdgcn_mfma_f32_16x16x32_bf16(af[mi], bfr[ni], acc[mi][ni], 0, 0, 0);
    }
    __syncthreads();
  }

  const ll cb = (ll)z * strideC;
  #pragma unroll
  for (int ni = 0; ni < 4; ++ni) {
    const int col = bn + wn + ni * 16 + lr;
    const float bv = (EPI != 0) ? bias[col] : 0.f;
    #pragma unroll
    for (int mi = 0; mi < 4; ++mi) {
      const int row0 = bm + wm + mi * 16 + lg * 4;
      if (EPI == 4) {
        const size_t o = ((size_t)z * N + col) * (size_t)M + row0;
        const float4 pv = *reinterpret_cast<const float4*>(pre + o);
        float4 r;
        r.x = acc[mi][ni][0] + bv + pv.x;
        r.y = acc[mi][ni][1] + bv + pv.y;
        r.z = acc[mi][ni][2] + bv + pv.z;
        r.w = acc[mi][ni][3] + bv + pv.w;
        *reinterpret_cast<float4*>(Cout + o) = r;
      } else {
        #pragma unroll
        for (int i = 0; i < 4; ++i) {
          float val = acc[mi][ni][i] + bv;
          if (EPI == 2) val = fmaxf(val, 0.f);
          Cout[cb + (ll)(row0 + i) * N + col] = val;
        }
      }
    }
  }
}

// ---------------- fused V kernel: V = X@wv + HM@w2 + bias  (K=512+512) ----------------
__global__ __launch_bounds__(256, 2) void gemm_vpe_k(
    const float* __restrict__ X, const float* __restrict__ HM,
    const float* __restrict__ wv, const float* __restrict__ w2,
    const float* __restrict__ bias, float* __restrict__ Cout)
{
  const int bm = blockIdx.y * 128;
  const int bn = blockIdx.x * 128;
  __shared__ alignas(16) char smem[32768];
  char* smA = smem;
  char* smB = smem + 16384;
  const int tid = threadIdx.x;
  const int lane = tid & 63, w = tid >> 6;
  const int lr = lane & 15, lg = lane >> 4;
  const int wm = (w & 1) * 64, wn = (w >> 1) * 64;

  f32x4 acc[4][4] = {};

  for (int k0 = 0; k0 < 1024; k0 += 64) {
    const float* A  = (k0 < 512) ? X  : HM;
    const float* Bw = (k0 < 512) ? wv : w2;
    const int kk = k0 & 511;
    #pragma unroll
    for (int p = 0; p < 8; ++p) {
      const int r = p * 16 + (tid >> 4);
      const int c = (tid & 15) * 4;
      const float4 v = *reinterpret_cast<const float4*>(A + (ll)(bm + r) * 512 + (kk + c));
      *reinterpret_cast<uint2*>(smA + r * 128 + ((c * 2) ^ sw16(r))) =
          make_uint2(pk2(v.x, v.y), pk2(v.z, v.w));
    }
    #pragma unroll
    for (int p = 0; p < 2; ++p) {
      const int bb = p * 256 + tid;
      const int nb = (bb & 31) * 4, kb = (bb >> 5) * 4;
      const float4 l0 = *reinterpret_cast<const float4*>(Bw + (ll)(kk + kb + 0) * 512 + (bn + nb));
      const float4 l1 = *reinterpret_cast<const float4*>(Bw + (ll)(kk + kb + 1) * 512 + (bn + nb));
      const float4 l2 = *reinterpret_cast<const float4*>(Bw + (ll)(kk + kb + 2) * 512 + (bn + nb));
      const float4 l3 = *reinterpret_cast<const float4*>(Bw + (ll)(kk + kb + 3) * 512 + (bn + nb));
      *reinterpret_cast<uint2*>(smB + (nb + 0) * 128 + ((kb * 2) ^ sw16(nb + 0))) = make_uint2(pk2(l0.x, l1.x), pk2(l2.x, l3.x));
      *reinterpret_cast<uint2*>(smB + (nb + 1) * 128 + ((kb * 2) ^ sw16(nb + 1))) = make_uint2(pk2(l0.y, l1.y), pk2(l2.y, l3.y));
      *reinterpret_cast<uint2*>(smB + (nb + 2) * 128 + ((kb * 2) ^ sw16(nb + 2))) = make_uint2(pk2(l0.z, l1.z), pk2(l2.z, l3.z));
      *reinterpret_cast<uint2*>(smB + (nb + 3) * 128 + ((kb * 2) ^ sw16(nb + 3))) = make_uint2(pk2(l0.w, l1.w), pk2(l2.w, l3.w));
    }
    __syncthreads();

    #pragma unroll
    for (int ks = 0; ks < 2; ++ks) {
      bf16x8 af[4], bfr[4];
      #pragma unroll
      for (int mi = 0; mi < 4; ++mi) {
        const int r = wm + mi * 16 + lr;
        af[mi] = *reinterpret_cast<const bf16x8*>(smA + r * 128 + ((((ks << 2) + lg) << 4) ^ sw16(r)));
      }
      #pragma unroll
      for (int ni = 0; ni < 4; ++ni) {
        const int r = wn + ni * 16 + lr;
        bfr[ni] = *reinterpret_cast<const bf16x8*>(smB + r * 128 + ((((ks << 2) + lg) << 4) ^ sw16(r)));
      }
      #pragma unroll
      for (int mi = 0; mi < 4; ++mi)
        #pragma unroll
        for (int ni = 0; ni < 4; ++ni)
          acc[mi][ni] = __builtin_amdgcn_mfma_f32_16x16x32_bf16(af[mi], bfr[ni], acc[mi][ni], 0, 0, 0);
    }
    __syncthreads();
  }

  #pragma unroll
  for (int ni = 0; ni < 4; ++ni) {
    const int col = bn + wn + ni * 16 + lr;
    const float bv = bias[col];
    #pragma unroll
    for (int mi = 0; mi < 4; ++mi) {
      const int row0 = bm + wm + mi * 16 + lg * 4;
      #pragma unroll
      for (int i = 0; i < 4; ++i)
        Cout[(ll)(row0 + i) * 512 + col] = acc[mi][ni][i] + bv;
    }
  }
}

// ---------------- fused branch-1 chain: P = (relu((X@WD2)@fgh1+b1))@fgh2+b2 ----------------
__device__ __forceinline__ void gemm128(const char* smA, const char* smW, int wrow, int lr, int lg,
                                        f32x4 acc[8]) {
  #pragma unroll
  for (int ks = 0; ks < 4; ++ks) {
    const int koff = (ks * 4 + lg) * 16;
    const int ra = wrow + lr;
    const bf16x8 a = *reinterpret_cast<const bf16x8*>(smA + ra * 256 + (koff ^ sw16(ra)));
    #pragma unroll
    for (int ni = 0; ni < 8; ++ni) {
      const int rn = ni * 16 + lr;
      const bf16x8 b = *reinterpret_cast<const bf16x8*>(smW + rn * 256 + (koff ^ sw16(rn)));
      acc[ni] = __builtin_amdgcn_mfma_f32_16x16x32_bf16(a, b, acc[ni], 0, 0, 0);
    }
  }
}

__device__ __forceinline__ void stageWT(const float* __restrict__ W, char* smW, int tid) {
  #pragma unroll
  for (int p = 0; p < 2; ++p) {
    const int bb = p * 512 + tid;
    const int nb = (bb & 31) * 4, kb = (bb >> 5) * 4;
    const float4 l0 = *reinterpret_cast<const float4*>(W + (kb + 0) * 128 + nb);
    const float4 l1 = *reinterpret_cast<const float4*>(W + (kb + 1) * 128 + nb);
    const float4 l2 = *reinterpret_cast<const float4*>(W + (kb + 2) * 128 + nb);
    const float4 l3 = *reinterpret_cast<const float4*>(W + (kb + 3) * 128 + nb);
    *reinterpret_cast<uint2*>(smW + (nb + 0) * 256 + ((kb * 2) ^ sw16(nb + 0))) = make_uint2(pk2(l0.x, l1.x), pk2(l2.x, l3.x));
    *reinterpret_cast<uint2*>(smW + (nb + 1) * 256 + ((kb * 2) ^ sw16(nb + 1))) = make_uint2(pk2(l0.y, l1.y), pk2(l2.y, l3.y));
    *reinterpret_cast<uint2*>(smW + (nb + 2) * 256 + ((kb * 2) ^ sw16(nb + 2))) = make_uint2(pk2(l0.z, l1.z), pk2(l2.z, l3.z));
    *reinterpret_cast<uint2*>(smW + (nb + 3) * 256 + ((kb * 2) ^ sw16(nb + 3))) = make_uint2(pk2(l0.w, l1.w), pk2(l2.w, l3.w));
  }
}

__global__ __launch_bounds__(512, 4) void fused1_k(
    const float* __restrict__ X,
    const float* __restrict__ wqs2, const float* __restrict__ wks2,
    const float* __restrict__ w2g, const float* __restrict__ b2g,
    const float* __restrict__ w3g, const float* __restrict__ b3g,
    float* __restrict__ P)
{
  __shared__ alignas(16) char smT[32768];
  __shared__ alignas(16) char smW[32768];
  const int tid = threadIdx.x;
  const int lane = tid & 63, w = tid >> 6;
  const int lr = lane & 15, lg = lane >> 4;
  const int wrow = w * 16;
  const ll blockRow = (ll)blockIdx.x * 128;
  const float* Xb = X + blockRow * 128;

  float b2r[8], b3r[8];
  #pragma unroll
  for (int ni = 0; ni < 8; ++ni) { b2r[ni] = b2g[ni * 16 + lr]; b3r[ni] = b3g[ni * 16 + lr]; }

  #pragma unroll
  for (int p = 0; p < 8; ++p) {
    const int i = p * 512 + tid;
    const int r = i >> 5, c4 = (i & 31) * 4;
    const float4 v = *reinterpret_cast<const float4*>(Xb + (ll)r * 128 + c4);
    *reinterpret_cast<uint2*>(smT + r * 256 + ((c4 * 2) ^ sw16(r))) =
        make_uint2(pk2(v.x, v.y), pk2(v.z, v.w));
  }
  #pragma unroll
  for (int p = 0; p < 2; ++p) {
    const int bb = p * 512 + tid;
    const int nb = (bb & 31) * 4, kb = (bb >> 5) * 4;
    float4 l0 = *reinterpret_cast<const float4*>(wqs2 + (kb + 0) * 128 + nb);
    float4 l1 = *reinterpret_cast<const float4*>(wqs2 + (kb + 1) * 128 + nb);
    float4 l2 = *reinterpret_cast<const float4*>(wqs2 + (kb + 2) * 128 + nb);
    float4 l3 = *reinterpret_cast<const float4*>(wqs2 + (kb + 3) * 128 + nb);
    const float4 m0 = *reinterpret_cast<const float4*>(wks2 + (kb + 0) * 128 + nb);
    const float4 m1 = *reinterpret_cast<const float4*>(wks2 + (kb + 1) * 128 + nb);
    const float4 m2 = *reinterpret_cast<const float4*>(wks2 + (kb + 2) * 128 + nb);
    const float4 m3 = *reinterpret_cast<const float4*>(wks2 + (kb + 3) * 128 + nb);
    l0.x -= m0.x; l0.y -= m0.y; l0.z -= m0.z; l0.w -= m0.w;
    l1.x -= m1.x; l1.y -= m1.y; l1.z -= m1.z; l1.w -= m1.w;
    l2.x -= m2.x; l2.y -= m2.y; l2.z -= m2.z; l2.w -= m2.w;
    l3.x -= m3.x; l3.y -= m3.y; l3.z -= m3.z; l3.w -= m3.w;
    *reinterpret_cast<uint2*>(smW + (nb + 0) * 256 + ((kb * 2) ^ sw16(nb + 0))) = make_uint2(pk2(l0.x, l1.x), pk2(l2.x, l3.x));
    *reinterpret_cast<uint2*>(smW + (nb + 1) * 256 + ((kb * 2) ^ sw16(nb + 1))) = make_uint2(pk2(l0.y, l1.y), pk2(l2.y, l3.y));
    *reinterpret_cast<uint2*>(smW + (nb + 2) * 256 + ((kb * 2) ^ sw16(nb + 2))) = make_uint2(pk2(l0.z, l1.z), pk2(l2.z, l3.z));
    *reinterpret_cast<uint2*>(smW + (nb + 3) * 256 + ((kb * 2) ^ sw16(nb + 3))) = make_uint2(pk2(l0.w, l1.w), pk2(l2.w, l3.w));
  }
  __syncthreads();

  f32x4 acc[8];
  #pragma unroll
  for (int ni = 0; ni < 8; ++ni) acc[ni] = f32x4{0.f, 0.f, 0.f, 0.f};
  gemm128(smT, smW, wrow, lr, lg, acc);        // T1 = X @ WD2
  __syncthreads();

  #pragma unroll
  for (int ni = 0; ni < 8; ++ni)
    #pragma unroll
    for (int i = 0; i < 4; ++i) {
      const int r = wrow + lg * 4 + i;
      *reinterpret_cast<unsigned short*>(smT + r * 256 + (((ni * 16 + lr) * 2) ^ sw16(r))) = bf1(acc[ni][i]);
    }
  stageWT(w2g, smW, tid);
  __syncthreads();

  #pragma unroll
  for (int ni = 0; ni < 8; ++ni) acc[ni] = f32x4{0.f, 0.f, 0.f, 0.f};
  gemm128(smT, smW, wrow, lr, lg, acc);        // U = T1 @ fgh1
  __syncthreads();

  #pragma unroll
  for (int ni = 0; ni < 8; ++ni)
    #pragma unroll
    for (int i = 0; i < 4; ++i) {
      const int r = wrow + lg * 4 + i;
      *reinterpret_cast<unsigned short*>(smT + r * 256 + (((ni * 16 + lr) * 2) ^ sw16(r))) =
          bf1(fmaxf(acc[ni][i] + b2r[ni], 0.f));
    }
  stageWT(w3g, smW, tid);
  __syncthreads();

  #pragma unroll
  for (int ni = 0; ni < 8; ++ni) acc[ni] = f32x4{0.f, 0.f, 0.f, 0.f};
  gemm128(smT, smW, wrow, lr, lg, acc);        // P = U @ fgh2

  #pragma unroll
  for (int ni = 0; ni < 8; ++ni)
    #pragma unroll
    for (int i = 0; i < 4; ++i) {
      const ll r = blockRow + wrow + lg * 4 + i;
      P[r * 128 + ni * 16 + lr] = acc[ni][i] + b3r[ni];
    }
}

// ---------------- online softmax partial reduce ----------------
__device__ inline void omax_upd(float& m, float& s, float v, float scale) {
  if (v > m) { s = s * expf((m - v) * scale) + 1.0f; m = v; }
  else       { s += expf((v - m) * scale); }
}
__device__ inline void omax_merge(float& m, float& s, float m2, float s2, float scale) {
  if (m2 > m) { s = s * expf((m - m2) * scale) + s2; m = m2; }
  else        { s += s2 * expf((m2 - m) * scale); }
}

__global__ __launch_bounds__(256) void red1_k(const float* __restrict__ P,
                                              float* __restrict__ PM, float* __restrict__ PS) {
  const int bid = blockIdx.x;
  const int b = bid >> 7, g = (bid >> 5) & 3, seg = bid & 31;
  const int d = threadIdx.x & 127, half = threadIdx.x >> 7;
  const size_t base = (size_t)b * NN * HH + g * GS1 + d;
  float m = -3.4e38f, s = 0.f;
  const int n0 = seg * 128 + half * 64;
  for (int n = n0; n < n0 + 64; ++n)
    omax_upd(m, s, P[base + (size_t)n * HH], SC1);
  __shared__ float sm[256], ss[256];
  sm[threadIdx.x] = m; ss[threadIdx.x] = s;
  __syncthreads();
  if (half == 0) {
    omax_merge(m, s, sm[threadIdx.x + 128], ss[threadIdx.x + 128], SC1);
    const int c = b * HH + g * GS1 + d;
    PM[(size_t)seg * 2048 + c] = m;
    PS[(size_t)seg * 2048 + c] = s;
  }
}

__global__ __launch_bounds__(256) void red2_k(const float* __restrict__ A2,
                                              float* __restrict__ PM, float* __restrict__ PS) {
  const int bid = blockIdx.x;
  const int b = bid >> 5, hb = (bid >> 3) & 3, seg = bid & 7;
  const int hl = threadIdx.x & 127, half = threadIdx.x >> 7;
  const int h = hb * 128 + hl;
  const size_t base = (size_t)b * 1024 * HH + h;
  float m = -3.4e38f, s = 0.f;
  const int r0 = seg * 128 + half * 64;
  for (int r = r0; r < r0 + 64; ++r)
    omax_upd(m, s, A2[base + (size_t)r * HH], SC2);
  __shared__ float sm[256], ss[256];
  sm[threadIdx.x] = m; ss[threadIdx.x] = s;
  __syncthreads();
  if (half == 0) {
    omax_merge(m, s, sm[threadIdx.x + 128], ss[threadIdx.x + 128], SC2);
    const int c = b * HH + h;
    PM[(size_t)seg * 2048 + c] = m;
    PS[(size_t)seg * 2048 + c] = s;
  }
}

__global__ __launch_bounds__(256) void combineN_k(const float* __restrict__ PM, const float* __restrict__ PS,
                                                  float* __restrict__ Mo, float* __restrict__ Ro,
                                                  int nseg, float scale) {
  const int c = blockIdx.x * 256 + threadIdx.x;
  float m = -3.4e38f, s = 0.f;
  for (int seg = 0; seg < nseg; ++seg)
    omax_merge(m, s, PM[(size_t)seg * 2048 + c], PS[(size_t)seg * 2048 + c], scale);
  Mo[c] = m;
  Ro[c] = 1.0f / s;
}

// ---------------- KNN: one wave per query, lane-min threshold + candidate sort ----------------
__global__ __launch_bounds__(512) void knn5_k(const float* __restrict__ xyz, int* __restrict__ idx) {
  const int blk = blockIdx.x;            // 2048 blocks, 512 per batch
  const int b = blk >> 9;
  const int q0 = (blk & 511) * 8;
  const float* xb = xyz + (size_t)b * NN * 3;
  const int tid = threadIdx.x;
  const int lane = tid & 63, w = tid >> 6;

  __shared__ float px[4096], py[4096], pz[4096];
  __shared__ unsigned short cand[8][64];
  __shared__ int cnt[8];

  #pragma unroll
  for (int i = 0; i < 8; ++i) {
    const int p = i * 512 + tid;
    px[p] = xb[p * 3];
    py[p] = xb[p * 3 + 1];
    pz[p] = xb[p * 3 + 2];
  }
  if (tid < 8) cnt[tid] = 0;
  __syncthreads();

  const int n = q0 + w;                  // query row (within batch)
  const float qx = px[n], qy = py[n], qz = pz[n];  // broadcast reads
  const float qn2 = fmaf(qz, qz, fmaf(qy, qy, qx * qx));

  // pass 1: per-lane min over 64 interleaved points
  ull best = ~0ull;
  #pragma unroll 8
  for (int i = 0; i < 64; ++i) {
    const int p = i * 64 + lane;
    const float ppx = px[p], ppy = py[p], ppz = pz[p];
    const float pn2 = fmaf(ppz, ppz, fmaf(ppy, ppy, ppx * ppx));
    const float dot = fmaf(qz, ppz, fmaf(qy, ppy, qx * ppx));
    const float dist = fmaf(-2.f, dot, qn2 + pn2);
    const unsigned u = __float_as_uint(dist);
    const unsigned key = u ^ (unsigned)(((int)u >> 31) | 0x80000000);
    const ull pk = ((ull)key << 12) | (unsigned)p;
    best = pk < best ? pk : best;
  }

  // bitonic sort 64 lane-minima (ascending)
  ull v = best;
  #pragma unroll
  for (int k = 2; k <= 64; k <<= 1) {
    #pragma unroll
    for (int j = k >> 1; j > 0; j >>= 1) {
      const ull o = __shfl_xor(v, j);
      const bool up = ((lane & k) == 0);
      const bool lower = ((lane & j) == 0);
      const bool keepMin = (lower == up);
      const bool oLess = o < v;
      v = (keepMin == oLess) ? o : v;
    }
  }
  const unsigned T32 = (unsigned)(__shfl(v, 9) >> 12);  // sortable key of 10th lane-min

  // pass 2: gather candidates with key <= T32
  #pragma unroll 8
  for (int i = 0; i < 64; ++i) {
    const int p = i * 64 + lane;
    const float ppx = px[p], ppy = py[p], ppz = pz[p];
    const float pn2 = fmaf(ppz, ppz, fmaf(ppy, ppy, ppx * ppx));
    const float dot = fmaf(qz, ppz, fmaf(qy, ppy, qx * ppx));
    const float dist = fmaf(-2.f, dot, qn2 + pn2);
    const unsigned u = __float_as_uint(dist);
    const unsigned key = u ^ (unsigned)(((int)u >> 31) | 0x80000000);
    if (key <= T32) {
      const int slot = atomicAdd(&cnt[w], 1);
      if (slot < 64) cand[w][slot] = (unsigned short)p;
    }
  }

  // exact sort of candidates
  const int c = cnt[w] < 64 ? cnt[w] : 64;
  ull cv = ~0ull;
  if (lane < c) {
    const int p = cand[w][lane];
    const float ppx = px[p], ppy = py[p], ppz = pz[p];
    const float pn2 = fmaf(ppz, ppz, fmaf(ppy, ppy, ppx * ppx));
    const float dot = fmaf(qz, ppz, fmaf(qy, ppy, qx * ppx));
    const float dist = fmaf(-2.f, dot, qn2 + pn2);
    const unsigned u = __float_as_uint(dist);
    const unsigned key = u ^ (unsigned)(((int)u >> 31) | 0x80000000);
    cv = ((ull)key << 12) | (unsigned)p;
  }
  #pragma unroll
  for (int k = 2; k <= 64; k <<= 1) {
    #pragma unroll
    for (int j = k >> 1; j > 0; j >>= 1) {
      const ull o = __shfl_xor(cv, j);
      const bool up = ((lane & k) == 0);
      const bool lower = ((lane & j) == 0);
      const bool keepMin = (lower == up);
      const bool oLess = o < cv;
      cv = (keepMin == oLess) ? o : cv;
    }
  }
  if (lane < KNN) idx[((size_t)(b * NN + n)) * KNN + lane] = (int)(cv & 0xFFFull);
}

// ---------------- pos-enc hidden mean ----------------
__global__ __launch_bounds__(256) void posenc_k(const float* __restrict__ xyz, const int* __restrict__ idx,
                                                const float* __restrict__ fd1w, const float* __restrict__ fd1b,
                                                float* __restrict__ hmean) {
  const int bn = blockIdx.x;
  const int b = bn >> 12, n = bn & (NN - 1);
  const float* xb = xyz + (size_t)b * NN * 3;
  const float qx = xb[n * 3], qy = xb[n * 3 + 1], qz = xb[n * 3 + 2];
  __shared__ float dxyz[KNN][3];
  if (threadIdx.x < KNN) {
    const int m = idx[(size_t)bn * KNN + threadIdx.x];
    dxyz[threadIdx.x][0] = qx - xb[m * 3];
    dxyz[threadIdx.x][1] = qy - xb[m * 3 + 1];
    dxyz[threadIdx.x][2] = qz - xb[m * 3 + 2];
  }
  __syncthreads();
  for (int h = threadIdx.x; h < HH; h += 256) {
    const float w0 = fd1w[h], w1 = fd1w[HH + h], w2 = fd1w[2 * HH + h], bb = fd1b[h];
    float acc = 0.f;
    #pragma unroll
    for (int k = 0; k < KNN; ++k)
      acc += fmaxf(fmaf(dxyz[k][2], w2, fmaf(dxyz[k][1], w1, dxyz[k][0] * w0)) + bb, 0.f);
    hmean[(size_t)bn * HH + h] = acc * 0.1f;
  }
}

// ---------------- res = (softmax1(P) + softmax2(A2)) * (v + posenc) ----------------
__global__ __launch_bounds__(256) void res_k(const float* __restrict__ P, const float* __restrict__ A2,
                                             const float* __restrict__ V,
                                             const float* __restrict__ M1, const float* __restrict__ R1,
                                             const float* __restrict__ M2, const float* __restrict__ R2,
                                             float* __restrict__ R) {
  const size_t i4 = (size_t)blockIdx.x * 256 + threadIdx.x;
  const size_t i = i4 * 4;
  const int b = (int)(i >> 21);
  const int n = (int)((i >> 9) & (NN - 1));
  const int h = (int)(i & (HH - 1));
  const int c = (b << 9) + h;
  const size_t j = (((size_t)b * 1024 + (n & 1023)) << 9) + h;
  const float4 p = *reinterpret_cast<const float4*>(P + i);
  const float4 a = *reinterpret_cast<const float4*>(A2 + j);
  const float4 v = *reinterpret_cast<const float4*>(V + i);
  const float4 m1 = *reinterpret_cast<const float4*>(M1 + c);
  const float4 r1 = *reinterpret_cast<const float4*>(R1 + c);
  const float4 m2 = *reinterpret_cast<const float4*>(M2 + c);
  const float4 r2 = *reinterpret_cast<const float4*>(R2 + c);
  float4 r;
  r.x = (expf((p.x - m1.x) * SC1) * r1.x + expf((a.x - m2.x) * SC2) * r2.x) * v.x;
  r.y = (expf((p.y - m1.y) * SC1) * r1.y + expf((a.y - m2.y) * SC2) * r2.y) * v.y;
  r.z = (expf((p.z - m1.z) * SC1) * r1.z + expf((a.z - m2.z) * SC2) * r2.z) * v.z;
  r.w = (expf((p.w - m1.w) * SC1) * r1.w + expf((a.w - m2.w) * SC2) * r2.w) * v.w;
  *reinterpret_cast<float4*>(R + i) = r;
}

__global__ void sub_k(const float* __restrict__ a, const float* __restrict__ b, float* __restrict__ o, int n) {
  const int i = blockIdx.x * 256 + threadIdx.x;
  if (i < n) o[i] = a[i] - b[i];
}

__global__ void copy_k(const float* __restrict__ a, float* __restrict__ o, int n) {
  const int i = blockIdx.x * 256 + threadIdx.x;
  if (i < n) o[i] = a[i];
}

extern "C" void kernel_launch(void* const* d_in, const int* in_sizes, int n_in,
                              void* d_out, int out_size, void* d_ws, size_t ws_size,
                              hipStream_t stream) {
  const float* features = (const float*)d_in[0];
  const float* xyz      = (const float*)d_in[1];
  const float* fc1_w    = (const float*)d_in[2];
  const float* fc1_b    = (const float*)d_in[3];
  const float* fc2_w    = (const float*)d_in[4];
  const float* fc2_b    = (const float*)d_in[5];
  const float* fd1_w    = (const float*)d_in[6];
  const float* fd1_b    = (const float*)d_in[7];
  const float* fd2_w    = (const float*)d_in[8];
  const float* fd2_b    = (const float*)d_in[9];
  const float* fg1_w    = (const float*)d_in[10];
  const float* fg1_b    = (const float*)d_in[11];
  const float* fg2_w    = (const float*)d_in[12];
  const float* fg2_b    = (const float*)d_in[13];
  const float* fgh1_w   = (const float*)d_in[14];
  const float* fgh1_b   = (const float*)d_in[15];
  const float* fgh2_w   = (const float*)d_in[16];
  const float* fgh2_b   = (const float*)d_in[17];
  const float* wqs      = (const float*)d_in[18];
  const float* wks      = (const float*)d_in[19];
  const float* wvs      = (const float*)d_in[20];
  const float* wqs2     = (const float*)d_in[21];
  const float* wks2     = (const float*)d_in[22];
  float* out = (float*)d_out;

  const size_t BNH = (size_t)BB * NN * HH;
  float* X   = (float*)d_ws;
  float* P   = X + BNH;
  float* Q   = P + BNH;      // posenc hidden-mean
  float* V   = Q + BNH;
  float* S1  = V + BNH;
  float* S2  = S1 + (size_t)BB * 1024 * HH;
  float* WD  = S2 + (size_t)BB * 1024 * HH;
  int*   IDX = (int*)(WD + HH * HH);
  float* PM1 = (float*)(IDX + (size_t)BB * NN * KNN);
  float* PS1 = PM1 + 32 * 2048;
  float* PM2 = PS1 + 32 * 2048;
  float* PS2 = PM2 + 8 * 2048;
  float* M1  = PS2 + 8 * 2048;
  float* R1  = M1 + 2048;
  float* M2  = R1 + 2048;
  float* R2  = M2 + 2048;
  const size_t need = ((char*)(R2 + 2048)) - (char*)d_ws;
  if (ws_size < need) {
    fprintf(stderr, "kernel_launch: ws too small: %zu < %zu\n", ws_size, need);
    return;
  }

  sub_k<<<(HH * HH + 255) / 256, 256, 0, stream>>>(wqs, wks, WD, HH * HH);

  // x = features^T @ fc1_w + fc1_b
  mgemm_k<true, 1><<<dim3(HH / 128, NN / 128, BB), 256, 0, stream>>>(
      features, fc1_w, fc1_b, X, nullptr, NN, HH, CC, NN, (ll)CC * NN, (ll)NN * HH);

  // branch 1 fused chain -> P
  fused1_k<<<512, 512, 0, stream>>>(X, wqs2, wks2, fgh1_w, fgh1_b, fgh2_w, fgh2_b, P);
  red1_k<<<512, 256, 0, stream>>>(P, PM1, PS1);
  combineN_k<<<8, 256, 0, stream>>>(PM1, PS1, M1, R1, 32, SC1);

  // branch 2
  mgemm_k<false, 0><<<dim3(HH / 128, 1024 / 128, BB), 256, 0, stream>>>(
      X + (size_t)3072 * HH, WD, nullptr, S1, nullptr, 1024, HH, HH, HH, (ll)NN * HH, (ll)1024 * HH);
  mgemm_k<false, 2><<<dim3(HH / 128, BB * 1024 / 128, 1), 256, 0, stream>>>(
      S1, fg1_w, fg1_b, S2, nullptr, BB * 1024, HH, HH, HH, 0, 0);
  mgemm_k<false, 1><<<dim3(HH / 128, BB * 1024 / 128, 1), 256, 0, stream>>>(
      S2, fg2_w, fg2_b, S1, nullptr, BB * 1024, HH, HH, HH, 0, 0);
  red2_k<<<128, 256, 0, stream>>>(S1, PM2, PS2);
  combineN_k<<<8, 256, 0, stream>>>(PM2, PS2, M2, R2, 8, SC2);

  // knn + pos-enc hidden mean
  knn5_k<<<BB * NN / 8, 512, 0, stream>>>(xyz, IDX);
  posenc_k<<<BB * NN, 256, 0, stream>>>(xyz, IDX, fd1_w, fd1_b, Q);

  // V = X@wvs + HM@fd2_w + fd2_b   (fused)
  gemm_vpe_k<<<dim3(HH / 128, BB * NN / 128, 1), 256, 0, stream>>>(
      X, Q, wvs, fd2_w, fd2_b, V);

  // res -> X
  res_k<<<(int)(BNH / 4 / 256), 256, 0, stream>>>(P, S1, V, M1, R1, M2, R2, X);

  // out = swap(res @ fc2_w + fc2_b) + features
  mgemm_k<false, 4><<<dim3(CC / 128, NN / 128, BB), 256, 0, stream>>>(
      X, fc2_w, fc2_b, out, features, NN, CC, HH, HH, (ll)NN * HH, 0);

  copy_k<<<(BB * NN * 3 + 255) / 256, 256, 0, stream>>>(xyz, out + (size_t)BB * CC * NN, BB * NN * 3);
}

// Round 7
// 293.125 us; speedup vs baseline: 4.3390x; 1.5890x over previous
//
#include <hip/hip_runtime.h>
#include <cstdio>

typedef long long ll;
typedef unsigned long long ull;
typedef unsigned short ushort_t;
typedef __bf16 bf16x8 __attribute__((ext_vector_type(8)));
typedef float f32x4 __attribute__((ext_vector_type(4)));

#define BB 4
#define NN 4096
#define CC 256
#define HH 512
#define GNUM 4
#define GS1 128
#define KNN 10

#define SC1 0.08838834764831845f   // 1/sqrt(128)
#define SC2 0.044194173824159216f  // 1/sqrt(512)

__device__ inline unsigned pk2(float x, float y) {
  unsigned a = __float_as_uint(x), b = __float_as_uint(y);
  a = (a + 0x7FFFu + ((a >> 16) & 1u)) >> 16;
  b = (b + 0x7FFFu + ((b >> 16) & 1u)) >> 16;
  return a | (b << 16);
}
__device__ inline ushort_t bf1(float x) {
  unsigned a = __float_as_uint(x);
  return (ushort_t)((a + 0x7FFFu + ((a >> 16) & 1u)) >> 16);
}
__device__ inline float b2f(ushort_t u) { return __uint_as_float((unsigned)u << 16); }
__device__ inline int sw16(int r) { return ((r ^ (r >> 3)) & 7) << 4; }

// chunked bijective XCD swizzle (nwg must be divisible by 8)
__device__ inline void xcd_map(int& bx, int& by, int& bz) {
  const int nx = gridDim.x, ny = gridDim.y;
  const int nwg = nx * ny * gridDim.z;
  const int bidf = blockIdx.x + nx * (blockIdx.y + ny * blockIdx.z);
  const int lid = (bidf & 7) * (nwg >> 3) + (bidf >> 3);
  bx = lid % nx;
  const int rem = lid / nx;
  by = rem % ny;
  bz = rem / ny;
}

// ---------------- bf16 MFMA GEMM ----------------
// ATRANS: A f32 stored [k][m]. ABF: A bf16 row-major [m][k].
// EPI: 0 store bf16, 1 +bias bf16, 2 +bias relu bf16, 4 +bias f32 transposed store + pre
template<bool ATRANS, bool ABF, int EPI>
__global__ __launch_bounds__(256, 2) void mgemm_k(
    const void* __restrict__ Ain, const float* __restrict__ Bw,
    const float* __restrict__ bias, void* __restrict__ CoutV,
    const float* __restrict__ pre,
    int M, int N, int K, int lda, ll strideA, ll strideC)
{
  int bx, by, z;
  xcd_map(bx, by, z);
  const int bm = by * 128;
  const int bn = bx * 128;
  __shared__ alignas(16) char smem[32768];
  char* smA = smem;
  char* smB = smem + 16384;
  const int tid = threadIdx.x;
  const int lane = tid & 63, w = tid >> 6;
  const int lr = lane & 15, lg = lane >> 4;
  const int wm = (w & 1) * 64, wn = (w >> 1) * 64;

  const ushort_t* Ab = ABF ? ((const ushort_t*)Ain + (ll)z * strideA) : nullptr;
  const float*    Af = ABF ? nullptr : ((const float*)Ain + (ll)z * strideA);

  f32x4 acc[4][4] = {};

  for (int k0 = 0; k0 < K; k0 += 64) {
    if (ABF) {
      #pragma unroll
      for (int p = 0; p < 4; ++p) {
        const int i = p * 256 + tid;
        const int r = i >> 3, c8 = (i & 7) * 8;
        const uint4 v = *reinterpret_cast<const uint4*>(Ab + (ll)(bm + r) * lda + (k0 + c8));
        *reinterpret_cast<uint4*>(smA + r * 128 + ((c8 * 2) ^ sw16(r))) = v;
      }
    } else if (ATRANS) {
      #pragma unroll
      for (int p = 0; p < 2; ++p) {
        const int bb = p * 256 + tid;
        const int mb = (bb & 31) * 4, kb = (bb >> 5) * 4;
        const float4 l0 = *reinterpret_cast<const float4*>(Af + (ll)(k0 + kb + 0) * lda + (bm + mb));
        const float4 l1 = *reinterpret_cast<const float4*>(Af + (ll)(k0 + kb + 1) * lda + (bm + mb));
        const float4 l2 = *reinterpret_cast<const float4*>(Af + (ll)(k0 + kb + 2) * lda + (bm + mb));
        const float4 l3 = *reinterpret_cast<const float4*>(Af + (ll)(k0 + kb + 3) * lda + (bm + mb));
        *reinterpret_cast<uint2*>(smA + (mb + 0) * 128 + ((kb * 2) ^ sw16(mb + 0))) = make_uint2(pk2(l0.x, l1.x), pk2(l2.x, l3.x));
        *reinterpret_cast<uint2*>(smA + (mb + 1) * 128 + ((kb * 2) ^ sw16(mb + 1))) = make_uint2(pk2(l0.y, l1.y), pk2(l2.y, l3.y));
        *reinterpret_cast<uint2*>(smA + (mb + 2) * 128 + ((kb * 2) ^ sw16(mb + 2))) = make_uint2(pk2(l0.z, l1.z), pk2(l2.z, l3.z));
        *reinterpret_cast<uint2*>(smA + (mb + 3) * 128 + ((kb * 2) ^ sw16(mb + 3))) = make_uint2(pk2(l0.w, l1.w), pk2(l2.w, l3.w));
      }
    }
    #pragma unroll
    for (int p = 0; p < 2; ++p) {
      const int bb = p * 256 + tid;
      const int nb = (bb & 31) * 4, kb = (bb >> 5) * 4;
      const float4 l0 = *reinterpret_cast<const float4*>(Bw + (ll)(k0 + kb + 0) * N + (bn + nb));
      const float4 l1 = *reinterpret_cast<const float4*>(Bw + (ll)(k0 + kb + 1) * N + (bn + nb));
      const float4 l2 = *reinterpret_cast<const float4*>(Bw + (ll)(k0 + kb + 2) * N + (bn + nb));
      const float4 l3 = *reinterpret_cast<const float4*>(Bw + (ll)(k0 + kb + 3) * N + (bn + nb));
      *reinterpret_cast<uint2*>(smB + (nb + 0) * 128 + ((kb * 2) ^ sw16(nb + 0))) = make_uint2(pk2(l0.x, l1.x), pk2(l2.x, l3.x));
      *reinterpret_cast<uint2*>(smB + (nb + 1) * 128 + ((kb * 2) ^ sw16(nb + 1))) = make_uint2(pk2(l0.y, l1.y), pk2(l2.y, l3.y));
      *reinterpret_cast<uint2*>(smB + (nb + 2) * 128 + ((kb * 2) ^ sw16(nb + 2))) = make_uint2(pk2(l0.z, l1.z), pk2(l2.z, l3.z));
      *reinterpret_cast<uint2*>(smB + (nb + 3) * 128 + ((kb * 2) ^ sw16(nb + 3))) = make_uint2(pk2(l0.w, l1.w), pk2(l2.w, l3.w));
    }
    __syncthreads();

    #pragma unroll
    for (int ks = 0; ks < 2; ++ks) {
      bf16x8 af[4], bfr[4];
      #pragma unroll
      for (int mi = 0; mi < 4; ++mi) {
        const int r = wm + mi * 16 + lr;
        af[mi] = *reinterpret_cast<const bf16x8*>(smA + r * 128 + ((((ks << 2) + lg) << 4) ^ sw16(r)));
      }
      #pragma unroll
      for (int ni = 0; ni < 4; ++ni) {
        const int r = wn + ni * 16 + lr;
        bfr[ni] = *reinterpret_cast<const bf16x8*>(smB + r * 128 + ((((ks << 2) + lg) << 4) ^ sw16(r)));
      }
      #pragma unroll
      for (int mi = 0; mi < 4; ++mi)
        #pragma unroll
        for (int ni = 0; ni < 4; ++ni)
          acc[mi][ni] = __builtin_amdgcn_mfma_f32_16x16x32_bf16(af[mi], bfr[ni], acc[mi][ni], 0, 0, 0);
    }
    __syncthreads();
  }

  #pragma unroll
  for (int ni = 0; ni < 4; ++ni) {
    const int col = bn + wn + ni * 16 + lr;
    const float bv = (EPI != 0) ? bias[col] : 0.f;
    #pragma unroll
    for (int mi = 0; mi < 4; ++mi) {
      const int row0 = bm + wm + mi * 16 + lg * 4;
      if (EPI == 4) {
        float* Cout = (float*)CoutV;
        const size_t o = ((size_t)z * N + col) * (size_t)M + row0;
        const float4 pv = *reinterpret_cast<const float4*>(pre + o);
        float4 r;
        r.x = acc[mi][ni][0] + bv + pv.x;
        r.y = acc[mi][ni][1] + bv + pv.y;
        r.z = acc[mi][ni][2] + bv + pv.z;
        r.w = acc[mi][ni][3] + bv + pv.w;
        *reinterpret_cast<float4*>(Cout + o) = r;
      } else {
        ushort_t* Co = (ushort_t*)CoutV + (ll)z * strideC;
        #pragma unroll
        for (int i = 0; i < 4; ++i) {
          float val = acc[mi][ni][i] + bv;
          if (EPI == 2) val = fmaxf(val, 0.f);
          Co[(ll)(row0 + i) * N + col] = bf1(val);
        }
      }
    }
  }
}

// ---------------- fused V kernel: V = X@wv + HM@w2 + bias (bf16 A, K=512+512) ----------------
__global__ __launch_bounds__(256, 2) void gemm_vpe_k(
    const ushort_t* __restrict__ X, const ushort_t* __restrict__ HM,
    const float* __restrict__ wv, const float* __restrict__ w2,
    const float* __restrict__ bias, ushort_t* __restrict__ Cout)
{
  int bx, by, z;
  xcd_map(bx, by, z);
  const int bm = by * 128;
  const int bn = bx * 128;
  __shared__ alignas(16) char smem[32768];
  char* smA = smem;
  char* smB = smem + 16384;
  const int tid = threadIdx.x;
  const int lane = tid & 63, w = tid >> 6;
  const int lr = lane & 15, lg = lane >> 4;
  const int wm = (w & 1) * 64, wn = (w >> 1) * 64;

  f32x4 acc[4][4] = {};

  for (int k0 = 0; k0 < 1024; k0 += 64) {
    const ushort_t* A = (k0 < 512) ? X : HM;
    const float* Bw = (k0 < 512) ? wv : w2;
    const int kk = k0 & 511;
    #pragma unroll
    for (int p = 0; p < 4; ++p) {
      const int i = p * 256 + tid;
      const int r = i >> 3, c8 = (i & 7) * 8;
      const uint4 v = *reinterpret_cast<const uint4*>(A + (ll)(bm + r) * 512 + (kk + c8));
      *reinterpret_cast<uint4*>(smA + r * 128 + ((c8 * 2) ^ sw16(r))) = v;
    }
    #pragma unroll
    for (int p = 0; p < 2; ++p) {
      const int bb = p * 256 + tid;
      const int nb = (bb & 31) * 4, kb = (bb >> 5) * 4;
      const float4 l0 = *reinterpret_cast<const float4*>(Bw + (ll)(kk + kb + 0) * 512 + (bn + nb));
      const float4 l1 = *reinterpret_cast<const float4*>(Bw + (ll)(kk + kb + 1) * 512 + (bn + nb));
      const float4 l2 = *reinterpret_cast<const float4*>(Bw + (ll)(kk + kb + 2) * 512 + (bn + nb));
      const float4 l3 = *reinterpret_cast<const float4*>(Bw + (ll)(kk + kb + 3) * 512 + (bn + nb));
      *reinterpret_cast<uint2*>(smB + (nb + 0) * 128 + ((kb * 2) ^ sw16(nb + 0))) = make_uint2(pk2(l0.x, l1.x), pk2(l2.x, l3.x));
      *reinterpret_cast<uint2*>(smB + (nb + 1) * 128 + ((kb * 2) ^ sw16(nb + 1))) = make_uint2(pk2(l0.y, l1.y), pk2(l2.y, l3.y));
      *reinterpret_cast<uint2*>(smB + (nb + 2) * 128 + ((kb * 2) ^ sw16(nb + 2))) = make_uint2(pk2(l0.z, l1.z), pk2(l2.z, l3.z));
      *reinterpret_cast<uint2*>(smB + (nb + 3) * 128 + ((kb * 2) ^ sw16(nb + 3))) = make_uint2(pk2(l0.w, l1.w), pk2(l2.w, l3.w));
    }
    __syncthreads();

    #pragma unroll
    for (int ks = 0; ks < 2; ++ks) {
      bf16x8 af[4], bfr[4];
      #pragma unroll
      for (int mi = 0; mi < 4; ++mi) {
        const int r = wm + mi * 16 + lr;
        af[mi] = *reinterpret_cast<const bf16x8*>(smA + r * 128 + ((((ks << 2) + lg) << 4) ^ sw16(r)));
      }
      #pragma unroll
      for (int ni = 0; ni < 4; ++ni) {
        const int r = wn + ni * 16 + lr;
        bfr[ni] = *reinterpret_cast<const bf16x8*>(smB + r * 128 + ((((ks << 2) + lg) << 4) ^ sw16(r)));
      }
      #pragma unroll
      for (int mi = 0; mi < 4; ++mi)
        #pragma unroll
        for (int ni = 0; ni < 4; ++ni)
          acc[mi][ni] = __builtin_amdgcn_mfma_f32_16x16x32_bf16(af[mi], bfr[ni], acc[mi][ni], 0, 0, 0);
    }
    __syncthreads();
  }

  #pragma unroll
  for (int ni = 0; ni < 4; ++ni) {
    const int col = bn + wn + ni * 16 + lr;
    const float bv = bias[col];
    #pragma unroll
    for (int mi = 0; mi < 4; ++mi) {
      const int row0 = bm + wm + mi * 16 + lg * 4;
      #pragma unroll
      for (int i = 0; i < 4; ++i)
        Cout[(ll)(row0 + i) * 512 + col] = bf1(acc[mi][ni][i] + bv);
    }
  }
}

// ---------------- fused branch-1 chain ----------------
__device__ __forceinline__ void gemm128(const char* smA, const char* smW, int wrow, int lr, int lg,
                                        f32x4 acc[8]) {
  #pragma unroll
  for (int ks = 0; ks < 4; ++ks) {
    const int koff = (ks * 4 + lg) * 16;
    const int ra = wrow + lr;
    const bf16x8 a = *reinterpret_cast<const bf16x8*>(smA + ra * 256 + (koff ^ sw16(ra)));
    #pragma unroll
    for (int ni = 0; ni < 8; ++ni) {
      const int rn = ni * 16 + lr;
      const bf16x8 b = *reinterpret_cast<const bf16x8*>(smW + rn * 256 + (koff ^ sw16(rn)));
      acc[ni] = __builtin_amdgcn_mfma_f32_16x16x32_bf16(a, b, acc[ni], 0, 0, 0);
    }
  }
}

__device__ __forceinline__ void stageWT(const float* __restrict__ W, char* smW, int tid) {
  #pragma unroll
  for (int p = 0; p < 2; ++p) {
    const int bb = p * 512 + tid;
    const int nb = (bb & 31) * 4, kb = (bb >> 5) * 4;
    const float4 l0 = *reinterpret_cast<const float4*>(W + (kb + 0) * 128 + nb);
    const float4 l1 = *reinterpret_cast<const float4*>(W + (kb + 1) * 128 + nb);
    const float4 l2 = *reinterpret_cast<const float4*>(W + (kb + 2) * 128 + nb);
    const float4 l3 = *reinterpret_cast<const float4*>(W + (kb + 3) * 128 + nb);
    *reinterpret_cast<uint2*>(smW + (nb + 0) * 256 + ((kb * 2) ^ sw16(nb + 0))) = make_uint2(pk2(l0.x, l1.x), pk2(l2.x, l3.x));
    *reinterpret_cast<uint2*>(smW + (nb + 1) * 256 + ((kb * 2) ^ sw16(nb + 1))) = make_uint2(pk2(l0.y, l1.y), pk2(l2.y, l3.y));
    *reinterpret_cast<uint2*>(smW + (nb + 2) * 256 + ((kb * 2) ^ sw16(nb + 2))) = make_uint2(pk2(l0.z, l1.z), pk2(l2.z, l3.z));
    *reinterpret_cast<uint2*>(smW + (nb + 3) * 256 + ((kb * 2) ^ sw16(nb + 3))) = make_uint2(pk2(l0.w, l1.w), pk2(l2.w, l3.w));
  }
}

__global__ __launch_bounds__(512, 4) void fused1_k(
    const ushort_t* __restrict__ X,
    const float* __restrict__ wqs2, const float* __restrict__ wks2,
    const float* __restrict__ w2g, const float* __restrict__ b2g,
    const float* __restrict__ w3g, const float* __restrict__ b3g,
    ushort_t* __restrict__ P)
{
  __shared__ alignas(16) char smT[32768];
  __shared__ alignas(16) char smW[32768];
  const int tid = threadIdx.x;
  const int lane = tid & 63, w = tid >> 6;
  const int lr = lane & 15, lg = lane >> 4;
  const int wrow = w * 16;
  const ll blockRow = (ll)blockIdx.x * 128;
  const ushort_t* Xb = X + blockRow * 128;

  float b2r[8], b3r[8];
  #pragma unroll
  for (int ni = 0; ni < 8; ++ni) { b2r[ni] = b2g[ni * 16 + lr]; b3r[ni] = b3g[ni * 16 + lr]; }

  // stage X tile [128r][128k] bf16 swizzled (direct bf16 loads)
  #pragma unroll
  for (int p = 0; p < 4; ++p) {
    const int i = p * 512 + tid;
    const int r = i >> 4, c8 = (i & 15) * 8;
    const uint4 v = *reinterpret_cast<const uint4*>(Xb + (ll)r * 128 + c8);
    *reinterpret_cast<uint4*>(smT + r * 256 + ((c8 * 2) ^ sw16(r))) = v;
  }
  #pragma unroll
  for (int p = 0; p < 2; ++p) {
    const int bb = p * 512 + tid;
    const int nb = (bb & 31) * 4, kb = (bb >> 5) * 4;
    float4 l0 = *reinterpret_cast<const float4*>(wqs2 + (kb + 0) * 128 + nb);
    float4 l1 = *reinterpret_cast<const float4*>(wqs2 + (kb + 1) * 128 + nb);
    float4 l2 = *reinterpret_cast<const float4*>(wqs2 + (kb + 2) * 128 + nb);
    float4 l3 = *reinterpret_cast<const float4*>(wqs2 + (kb + 3) * 128 + nb);
    const float4 m0 = *reinterpret_cast<const float4*>(wks2 + (kb + 0) * 128 + nb);
    const float4 m1 = *reinterpret_cast<const float4*>(wks2 + (kb + 1) * 128 + nb);
    const float4 m2 = *reinterpret_cast<const float4*>(wks2 + (kb + 2) * 128 + nb);
    const float4 m3 = *reinterpret_cast<const float4*>(wks2 + (kb + 3) * 128 + nb);
    l0.x -= m0.x; l0.y -= m0.y; l0.z -= m0.z; l0.w -= m0.w;
    l1.x -= m1.x; l1.y -= m1.y; l1.z -= m1.z; l1.w -= m1.w;
    l2.x -= m2.x; l2.y -= m2.y; l2.z -= m2.z; l2.w -= m2.w;
    l3.x -= m3.x; l3.y -= m3.y; l3.z -= m3.z; l3.w -= m3.w;
    *reinterpret_cast<uint2*>(smW + (nb + 0) * 256 + ((kb * 2) ^ sw16(nb + 0))) = make_uint2(pk2(l0.x, l1.x), pk2(l2.x, l3.x));
    *reinterpret_cast<uint2*>(smW + (nb + 1) * 256 + ((kb * 2) ^ sw16(nb + 1))) = make_uint2(pk2(l0.y, l1.y), pk2(l2.y, l3.y));
    *reinterpret_cast<uint2*>(smW + (nb + 2) * 256 + ((kb * 2) ^ sw16(nb + 2))) = make_uint2(pk2(l0.z, l1.z), pk2(l2.z, l3.z));
    *reinterpret_cast<uint2*>(smW + (nb + 3) * 256 + ((kb * 2) ^ sw16(nb + 3))) = make_uint2(pk2(l0.w, l1.w), pk2(l2.w, l3.w));
  }
  __syncthreads();

  f32x4 acc[8];
  #pragma unroll
  for (int ni = 0; ni < 8; ++ni) acc[ni] = f32x4{0.f, 0.f, 0.f, 0.f};
  gemm128(smT, smW, wrow, lr, lg, acc);        // T1 = X @ WD2
  __syncthreads();

  #pragma unroll
  for (int ni = 0; ni < 8; ++ni)
    #pragma unroll
    for (int i = 0; i < 4; ++i) {
      const int r = wrow + lg * 4 + i;
      *reinterpret_cast<ushort_t*>(smT + r * 256 + (((ni * 16 + lr) * 2) ^ sw16(r))) = bf1(acc[ni][i]);
    }
  stageWT(w2g, smW, tid);
  __syncthreads();

  #pragma unroll
  for (int ni = 0; ni < 8; ++ni) acc[ni] = f32x4{0.f, 0.f, 0.f, 0.f};
  gemm128(smT, smW, wrow, lr, lg, acc);        // U = T1 @ fgh1
  __syncthreads();

  #pragma unroll
  for (int ni = 0; ni < 8; ++ni)
    #pragma unroll
    for (int i = 0; i < 4; ++i) {
      const int r = wrow + lg * 4 + i;
      *reinterpret_cast<ushort_t*>(smT + r * 256 + (((ni * 16 + lr) * 2) ^ sw16(r))) =
          bf1(fmaxf(acc[ni][i] + b2r[ni], 0.f));
    }
  stageWT(w3g, smW, tid);
  __syncthreads();

  #pragma unroll
  for (int ni = 0; ni < 8; ++ni) acc[ni] = f32x4{0.f, 0.f, 0.f, 0.f};
  gemm128(smT, smW, wrow, lr, lg, acc);        // P = U @ fgh2

  #pragma unroll
  for (int ni = 0; ni < 8; ++ni)
    #pragma unroll
    for (int i = 0; i < 4; ++i) {
      const ll r = blockRow + wrow + lg * 4 + i;
      P[r * 128 + ni * 16 + lr] = bf1(acc[ni][i] + b3r[ni]);
    }
}

// ---------------- online softmax partial reduce (bf16 inputs) ----------------
__device__ inline void omax_upd(float& m, float& s, float v, float scale) {
  if (v > m) { s = s * expf((m - v) * scale) + 1.0f; m = v; }
  else       { s += expf((v - m) * scale); }
}
__device__ inline void omax_merge(float& m, float& s, float m2, float s2, float scale) {
  if (m2 > m) { s = s * expf((m - m2) * scale) + s2; m = m2; }
  else        { s += s2 * expf((m2 - m) * scale); }
}

__global__ __launch_bounds__(256) void red1_k(const ushort_t* __restrict__ P,
                                              float* __restrict__ PM, float* __restrict__ PS) {
  const int bid = blockIdx.x;
  const int b = bid >> 7, g = (bid >> 5) & 3, seg = bid & 31;
  const int d = threadIdx.x & 127, half = threadIdx.x >> 7;
  const size_t base = (size_t)b * NN * HH + g * GS1 + d;
  float m = -3.4e38f, s = 0.f;
  const int n0 = seg * 128 + half * 64;
  for (int n = n0; n < n0 + 64; ++n)
    omax_upd(m, s, b2f(P[base + (size_t)n * HH]), SC1);
  __shared__ float sm[256], ss[256];
  sm[threadIdx.x] = m; ss[threadIdx.x] = s;
  __syncthreads();
  if (half == 0) {
    omax_merge(m, s, sm[threadIdx.x + 128], ss[threadIdx.x + 128], SC1);
    const int c = b * HH + g * GS1 + d;
    PM[(size_t)seg * 2048 + c] = m;
    PS[(size_t)seg * 2048 + c] = s;
  }
}

__global__ __launch_bounds__(256) void red2_k(const ushort_t* __restrict__ A2,
                                              float* __restrict__ PM, float* __restrict__ PS) {
  const int bid = blockIdx.x;
  const int b = bid >> 5, hb = (bid >> 3) & 3, seg = bid & 7;
  const int hl = threadIdx.x & 127, half = threadIdx.x >> 7;
  const int h = hb * 128 + hl;
  const size_t base = (size_t)b * 1024 * HH + h;
  float m = -3.4e38f, s = 0.f;
  const int r0 = seg * 128 + half * 64;
  for (int r = r0; r < r0 + 64; ++r)
    omax_upd(m, s, b2f(A2[base + (size_t)r * HH]), SC2);
  __shared__ float sm[256], ss[256];
  sm[threadIdx.x] = m; ss[threadIdx.x] = s;
  __syncthreads();
  if (half == 0) {
    omax_merge(m, s, sm[threadIdx.x + 128], ss[threadIdx.x + 128], SC2);
    const int c = b * HH + h;
    PM[(size_t)seg * 2048 + c] = m;
    PS[(size_t)seg * 2048 + c] = s;
  }
}

__global__ __launch_bounds__(256) void combineN_k(const float* __restrict__ PM, const float* __restrict__ PS,
                                                  float* __restrict__ Mo, float* __restrict__ Ro,
                                                  int nseg, float scale) {
  const int c = blockIdx.x * 256 + threadIdx.x;
  float m = -3.4e38f, s = 0.f;
  for (int seg = 0; seg < nseg; ++seg)
    omax_merge(m, s, PM[(size_t)seg * 2048 + c], PS[(size_t)seg * 2048 + c], scale);
  Mo[c] = m;
  Ro[c] = 1.0f / s;
}

// ---------------- KNN: one wave per query, lane-min threshold + candidate sort ----------------
__global__ __launch_bounds__(512) void knn5_k(const float* __restrict__ xyz, int* __restrict__ idx) {
  const int blk = blockIdx.x;
  const int b = blk >> 9;
  const int q0 = (blk & 511) * 8;
  const float* xb = xyz + (size_t)b * NN * 3;
  const int tid = threadIdx.x;
  const int lane = tid & 63, w = tid >> 6;

  __shared__ float px[4096], py[4096], pz[4096];
  __shared__ unsigned short cand[8][64];
  __shared__ int cnt[8];

  #pragma unroll
  for (int i = 0; i < 8; ++i) {
    const int p = i * 512 + tid;
    px[p] = xb[p * 3];
    py[p] = xb[p * 3 + 1];
    pz[p] = xb[p * 3 + 2];
  }
  if (tid < 8) cnt[tid] = 0;
  __syncthreads();

  const int n = q0 + w;
  const float qx = px[n], qy = py[n], qz = pz[n];
  const float qn2 = fmaf(qz, qz, fmaf(qy, qy, qx * qx));

  ull best = ~0ull;
  #pragma unroll 8
  for (int i = 0; i < 64; ++i) {
    const int p = i * 64 + lane;
    const float ppx = px[p], ppy = py[p], ppz = pz[p];
    const float pn2 = fmaf(ppz, ppz, fmaf(ppy, ppy, ppx * ppx));
    const float dot = fmaf(qz, ppz, fmaf(qy, ppy, qx * ppx));
    const float dist = fmaf(-2.f, dot, qn2 + pn2);
    const unsigned u = __float_as_uint(dist);
    const unsigned key = u ^ (unsigned)(((int)u >> 31) | 0x80000000);
    const ull pk = ((ull)key << 12) | (unsigned)p;
    best = pk < best ? pk : best;
  }

  ull v = best;
  #pragma unroll
  for (int k = 2; k <= 64; k <<= 1) {
    #pragma unroll
    for (int j = k >> 1; j > 0; j >>= 1) {
      const ull o = __shfl_xor(v, j);
      const bool up = ((lane & k) == 0);
      const bool lower = ((lane & j) == 0);
      const bool keepMin = (lower == up);
      const bool oLess = o < v;
      v = (keepMin == oLess) ? o : v;
    }
  }
  const unsigned T32 = (unsigned)(__shfl(v, 9) >> 12);

  #pragma unroll 8
  for (int i = 0; i < 64; ++i) {
    const int p = i * 64 + lane;
    const float ppx = px[p], ppy = py[p], ppz = pz[p];
    const float pn2 = fmaf(ppz, ppz, fmaf(ppy, ppy, ppx * ppx));
    const float dot = fmaf(qz, ppz, fmaf(qy, ppy, qx * ppx));
    const float dist = fmaf(-2.f, dot, qn2 + pn2);
    const unsigned u = __float_as_uint(dist);
    const unsigned key = u ^ (unsigned)(((int)u >> 31) | 0x80000000);
    if (key <= T32) {
      const int slot = atomicAdd(&cnt[w], 1);
      if (slot < 64) cand[w][slot] = (unsigned short)p;
    }
  }

  const int c = cnt[w] < 64 ? cnt[w] : 64;
  ull cv = ~0ull;
  if (lane < c) {
    const int p = cand[w][lane];
    const float ppx = px[p], ppy = py[p], ppz = pz[p];
    const float pn2 = fmaf(ppz, ppz, fmaf(ppy, ppy, ppx * ppx));
    const float dot = fmaf(qz, ppz, fmaf(qy, ppy, qx * ppx));
    const float dist = fmaf(-2.f, dot, qn2 + pn2);
    const unsigned u = __float_as_uint(dist);
    const unsigned key = u ^ (unsigned)(((int)u >> 31) | 0x80000000);
    cv = ((ull)key << 12) | (unsigned)p;
  }
  #pragma unroll
  for (int k = 2; k <= 64; k <<= 1) {
    #pragma unroll
    for (int j = k >> 1; j > 0; j >>= 1) {
      const ull o = __shfl_xor(cv, j);
      const bool up = ((lane & k) == 0);
      const bool lower = ((lane & j) == 0);
      const bool keepMin = (lower == up);
      const bool oLess = o < cv;
      cv = (keepMin == oLess) ? o : cv;
    }
  }
  if (lane < KNN) idx[((size_t)(b * NN + n)) * KNN + lane] = (int)(cv & 0xFFFull);
}

// ---------------- pos-enc hidden mean (bf16 out) ----------------
__global__ __launch_bounds__(256) void posenc_k(const float* __restrict__ xyz, const int* __restrict__ idx,
                                                const float* __restrict__ fd1w, const float* __restrict__ fd1b,
                                                ushort_t* __restrict__ hmean) {
  const int bn = blockIdx.x;
  const int b = bn >> 12, n = bn & (NN - 1);
  const float* xb = xyz + (size_t)b * NN * 3;
  const float qx = xb[n * 3], qy = xb[n * 3 + 1], qz = xb[n * 3 + 2];
  __shared__ float dxyz[KNN][3];
  if (threadIdx.x < KNN) {
    const int m = idx[(size_t)bn * KNN + threadIdx.x];
    dxyz[threadIdx.x][0] = qx - xb[m * 3];
    dxyz[threadIdx.x][1] = qy - xb[m * 3 + 1];
    dxyz[threadIdx.x][2] = qz - xb[m * 3 + 2];
  }
  __syncthreads();
  for (int h = threadIdx.x; h < HH; h += 256) {
    const float w0 = fd1w[h], w1 = fd1w[HH + h], w2 = fd1w[2 * HH + h], bb = fd1b[h];
    float acc = 0.f;
    #pragma unroll
    for (int k = 0; k < KNN; ++k)
      acc += fmaxf(fmaf(dxyz[k][2], w2, fmaf(dxyz[k][1], w1, dxyz[k][0] * w0)) + bb, 0.f);
    hmean[(size_t)bn * HH + h] = bf1(acc * 0.1f);
  }
}

// ---------------- res = (softmax1(P) + softmax2(A2)) * V  -> bf16 ----------------
__global__ __launch_bounds__(256) void res_k(const ushort_t* __restrict__ P, const ushort_t* __restrict__ A2,
                                             const ushort_t* __restrict__ V,
                                             const float* __restrict__ M1, const float* __restrict__ R1,
                                             const float* __restrict__ M2, const float* __restrict__ R2,
                                             ushort_t* __restrict__ R) {
  const size_t i8 = (size_t)blockIdx.x * 256 + threadIdx.x;
  const size_t i = i8 * 8;
  const int b = (int)(i >> 21);
  const int n = (int)((i >> 9) & (NN - 1));
  const int h = (int)(i & (HH - 1));
  const int c = (b << 9) + h;
  const size_t j = (((size_t)b * 1024 + (n & 1023)) << 9) + h;
  const uint4 pu = *reinterpret_cast<const uint4*>(P + i);
  const uint4 au = *reinterpret_cast<const uint4*>(A2 + j);
  const uint4 vu = *reinterpret_cast<const uint4*>(V + i);
  float m1[8], r1[8], m2[8], r2[8];
  *reinterpret_cast<float4*>(m1) = *reinterpret_cast<const float4*>(M1 + c);
  *reinterpret_cast<float4*>(m1 + 4) = *reinterpret_cast<const float4*>(M1 + c + 4);
  *reinterpret_cast<float4*>(r1) = *reinterpret_cast<const float4*>(R1 + c);
  *reinterpret_cast<float4*>(r1 + 4) = *reinterpret_cast<const float4*>(R1 + c + 4);
  *reinterpret_cast<float4*>(m2) = *reinterpret_cast<const float4*>(M2 + c);
  *reinterpret_cast<float4*>(m2 + 4) = *reinterpret_cast<const float4*>(M2 + c + 4);
  *reinterpret_cast<float4*>(r2) = *reinterpret_cast<const float4*>(R2 + c);
  *reinterpret_cast<float4*>(r2 + 4) = *reinterpret_cast<const float4*>(R2 + c + 4);
  const unsigned* pw = reinterpret_cast<const unsigned*>(&pu);
  const unsigned* aw = reinterpret_cast<const unsigned*>(&au);
  const unsigned* vw = reinterpret_cast<const unsigned*>(&vu);
  float r[8];
  #pragma unroll
  for (int e = 0; e < 8; ++e) {
    const unsigned wsel = (e >> 1);
    const ushort_t pv = (ushort_t)((pw[wsel] >> ((e & 1) * 16)) & 0xFFFF);
    const ushort_t av = (ushort_t)((aw[wsel] >> ((e & 1) * 16)) & 0xFFFF);
    const ushort_t vv = (ushort_t)((vw[wsel] >> ((e & 1) * 16)) & 0xFFFF);
    r[e] = (expf((b2f(pv) - m1[e]) * SC1) * r1[e] + expf((b2f(av) - m2[e]) * SC2) * r2[e]) * b2f(vv);
  }
  uint4 ru;
  ru.x = pk2(r[0], r[1]);
  ru.y = pk2(r[2], r[3]);
  ru.z = pk2(r[4], r[5]);
  ru.w = pk2(r[6], r[7]);
  *reinterpret_cast<uint4*>(R + i) = ru;
}

__global__ void sub_k(const float* __restrict__ a, const float* __restrict__ b, float* __restrict__ o, int n) {
  const int i = blockIdx.x * 256 + threadIdx.x;
  if (i < n) o[i] = a[i] - b[i];
}

__global__ void copy_k(const float* __restrict__ a, float* __restrict__ o, int n) {
  const int i = blockIdx.x * 256 + threadIdx.x;
  if (i < n) o[i] = a[i];
}

extern "C" void kernel_launch(void* const* d_in, const int* in_sizes, int n_in,
                              void* d_out, int out_size, void* d_ws, size_t ws_size,
                              hipStream_t stream) {
  const float* features = (const float*)d_in[0];
  const float* xyz      = (const float*)d_in[1];
  const float* fc1_w    = (const float*)d_in[2];
  const float* fc1_b    = (const float*)d_in[3];
  const float* fc2_w    = (const float*)d_in[4];
  const float* fc2_b    = (const float*)d_in[5];
  const float* fd1_w    = (const float*)d_in[6];
  const float* fd1_b    = (const float*)d_in[7];
  const float* fd2_w    = (const float*)d_in[8];
  const float* fd2_b    = (const float*)d_in[9];
  const float* fg1_w    = (const float*)d_in[10];
  const float* fg1_b    = (const float*)d_in[11];
  const float* fg2_w    = (const float*)d_in[12];
  const float* fg2_b    = (const float*)d_in[13];
  const float* fgh1_w   = (const float*)d_in[14];
  const float* fgh1_b   = (const float*)d_in[15];
  const float* fgh2_w   = (const float*)d_in[16];
  const float* fgh2_b   = (const float*)d_in[17];
  const float* wqs      = (const float*)d_in[18];
  const float* wks      = (const float*)d_in[19];
  const float* wvs      = (const float*)d_in[20];
  const float* wqs2     = (const float*)d_in[21];
  const float* wks2     = (const float*)d_in[22];
  float* out = (float*)d_out;

  const size_t BNH = (size_t)BB * NN * HH;       // 8388608
  // f32 region first
  float* WD  = (float*)d_ws;                     // 512*512
  float* PM1 = WD + (size_t)HH * HH;
  float* PS1 = PM1 + 32 * 2048;
  float* PM2 = PS1 + 32 * 2048;
  float* PS2 = PM2 + 8 * 2048;
  float* M1  = PS2 + 8 * 2048;
  float* R1  = M1 + 2048;
  float* M2  = R1 + 2048;
  float* R2  = M2 + 2048;
  int*   IDX = (int*)(R2 + 2048);
  // bf16 region
  ushort_t* Xh = (ushort_t*)(IDX + (size_t)BB * NN * KNN);
  ushort_t* P  = Xh + BNH;
  ushort_t* HM = P + BNH;
  ushort_t* V  = HM + BNH;
  ushort_t* R  = V + BNH;
  ushort_t* S1 = R + BNH;
  ushort_t* S2 = S1 + (size_t)BB * 1024 * HH;
  const size_t need = ((char*)(S2 + (size_t)BB * 1024 * HH)) - (char*)d_ws;
  if (ws_size < need) {
    fprintf(stderr, "kernel_launch: ws too small: %zu < %zu\n", ws_size, need);
    return;
  }

  sub_k<<<(HH * HH + 255) / 256, 256, 0, stream>>>(wqs, wks, WD, HH * HH);

  // x = features^T @ fc1_w + fc1_b  -> Xh (bf16)
  mgemm_k<true, false, 1><<<dim3(HH / 128, NN / 128, BB), 256, 0, stream>>>(
      features, fc1_w, fc1_b, Xh, nullptr, NN, HH, CC, NN, (ll)CC * NN, (ll)NN * HH);

  // branch 1 fused chain -> P (bf16)
  fused1_k<<<512, 512, 0, stream>>>(Xh, wqs2, wks2, fgh1_w, fgh1_b, fgh2_w, fgh2_b, P);
  red1_k<<<512, 256, 0, stream>>>(P, PM1, PS1);
  combineN_k<<<8, 256, 0, stream>>>(PM1, PS1, M1, R1, 32, SC1);

  // branch 2 (bf16 A)
  mgemm_k<false, true, 0><<<dim3(HH / 128, 1024 / 128, BB), 256, 0, stream>>>(
      Xh + (size_t)3072 * HH, WD, nullptr, S1, nullptr, 1024, HH, HH, HH, (ll)NN * HH, (ll)1024 * HH);
  mgemm_k<false, true, 2><<<dim3(HH / 128, BB * 1024 / 128, 1), 256, 0, stream>>>(
      S1, fg1_w, fg1_b, S2, nullptr, BB * 1024, HH, HH, HH, 0, 0);
  mgemm_k<false, true, 1><<<dim3(HH / 128, BB * 1024 / 128, 1), 256, 0, stream>>>(
      S2, fg2_w, fg2_b, S1, nullptr, BB * 1024, HH, HH, HH, 0, 0);
  red2_k<<<128, 256, 0, stream>>>(S1, PM2, PS2);
  combineN_k<<<8, 256, 0, stream>>>(PM2, PS2, M2, R2, 8, SC2);

  // knn + pos-enc hidden mean
  knn5_k<<<BB * NN / 8, 512, 0, stream>>>(xyz, IDX);
  posenc_k<<<BB * NN, 256, 0, stream>>>(xyz, IDX, fd1_w, fd1_b, HM);

  // V = Xh@wvs + HM@fd2_w + fd2_b (bf16)
  gemm_vpe_k<<<dim3(HH / 128, BB * NN / 128, 1), 256, 0, stream>>>(
      Xh, HM, wvs, fd2_w, fd2_b, V);

  // res -> R (bf16)
  res_k<<<(int)(BNH / 8 / 256), 256, 0, stream>>>(P, S1, V, M1, R1, M2, R2, R);

  // out = swap(res @ fc2_w + fc2_b) + features (f32)
  mgemm_k<false, true, 4><<<dim3(CC / 128, NN / 128, BB), 256, 0, stream>>>(
      R, fc2_w, fc2_b, out, features, NN, CC, HH, HH, (ll)NN * HH, 0);

  copy_k<<<(BB * NN * 3 + 255) / 256, 256, 0, stream>>>(xyz, out + (size_t)BB * CC * NN, BB * NN * 3);
}